// Round 5
// baseline (1190.351 us; speedup 1.0000x reference)
//
#include <hip/hip_runtime.h>

typedef _Float16 f16;
typedef _Float16 f16x8 __attribute__((ext_vector_type(8)));
typedef _Float16 f16x4 __attribute__((ext_vector_type(4)));
typedef _Float16 f16x2 __attribute__((ext_vector_type(2)));
typedef float f32x4 __attribute__((ext_vector_type(4)));
typedef float f32x2 __attribute__((ext_vector_type(2)));

#define MFMA16(a, b, c) __builtin_amdgcn_mfma_f32_16x16x32_f16(a, b, c, 0, 0, 0)

#define HID 4096
#define ROWS 128      // B*S
#define SCL 0.12751743f  // (1/sqrt(128)) * log2(e)

// ===== MEASUREMENT ROUND: internal repeat factors to surface kernels in =====
// ===== rocprof top-5 (must exceed ~320us harness fills). Results are   =====
// ===== identical to x1 (reps reinit accumulators; last rep is real).   =====
#define ATTN_REPS 4
#define PROJ_REPS 16   // (PROJ_REPS-1) % 3 == 0 so last rep uses the right W

__device__ __forceinline__ f16x8 cvt8(float4 x, float4 y) {
    f16x8 v = {(f16)x.x, (f16)x.y, (f16)x.z, (f16)x.w,
               (f16)y.x, (f16)y.y, (f16)y.z, (f16)y.w};
    return v;
}

// XOR swizzle for a tile with 128 f16 (256 B) row pitch
__device__ __forceinline__ int swz2(int row, int cb) {
    return row * 256 + (cb ^ ((row & 7) << 4));
}

// ---------------- kernel 0: h fp32 -> f16 ----------------
__global__ void k_cvt(const float* __restrict__ src, f16* __restrict__ dst) {
    const int i = blockIdx.x * blockDim.x + threadIdx.x;
    const float4* s4 = (const float4*)src + (size_t)i * 2;
    float4 x = s4[0], y = s4[1];
    *((f16x8*)dst + i) = cvt8(x, y);
}

// ---------------- kernel A: fused QKV projection (R2 + rep loop) ----------------
__global__ __launch_bounds__(256) void k_proj(
        const f16* __restrict__ hb,
        const float* __restrict__ Wq, const float* __restrict__ Wk,
        const float* __restrict__ Wv,
        f16* __restrict__ Qw, f16* __restrict__ Kw, f16* __restrict__ Vw) {
    const int mat = blockIdx.x >> 8;
    const int ct  = blockIdx.x & 255;
    f16* __restrict__ Ob = (mat == 0) ? Qw : (mat == 1) ? Kw : Vw;
    const int c0 = ct * 16;

    __shared__ __align__(16) f16 sA[128 * 128];
    __shared__ __align__(16) f16 sB[16 * 128];

    const int tid = threadIdx.x;
    const int w = tid >> 6, l = tid & 63;
    const int rw = w * 32;
    const int ar = tid >> 4;
    const int ac = (tid & 15) * 8;

    f32x4 acc0, acc1;

    for (int rep = 0; rep < PROJ_REPS; ++rep) {
        // rotate W so reps stream different 67MB (defeats trivial L3 reuse);
        // last rep: (mat + PROJ_REPS-1) % 3 == mat  -> correct matrix
        const int matr = (mat + rep) % 3;
        const float* __restrict__ W = (matr == 0) ? Wq : (matr == 1) ? Wk : Wv;

        acc0 = (f32x4){}; acc1 = (f32x4){};

        float4 wx, wy;
        f16x8 hreg[8];
        {
            const float* wp = W + (size_t)(c0 + ar) * HID + ac;
            wx = *(const float4*)wp; wy = *(const float4*)(wp + 4);
            #pragma unroll
            for (int c = 0; c < 8; ++c)
                hreg[c] = *(const f16x8*)(hb + (size_t)(c * 16 + ar) * HID + ac);
        }

        for (int ks = 0; ks < 32; ++ks) {
            #pragma unroll
            for (int c = 0; c < 8; ++c)
                *(f16x8*)((char*)sA + swz2(c * 16 + ar, ac * 2)) = hreg[c];
            *(f16x8*)((char*)sB + swz2(ar, ac * 2)) = cvt8(wx, wy);
            __syncthreads();
            if (ks < 31) {
                const int k0 = (ks + 1) * 128;
                const float* wp = W + (size_t)(c0 + ar) * HID + k0 + ac;
                wx = *(const float4*)wp; wy = *(const float4*)(wp + 4);
                #pragma unroll
                for (int c = 0; c < 8; ++c)
                    hreg[c] = *(const f16x8*)(hb + (size_t)(c * 16 + ar) * HID + k0 + ac);
            }
            #pragma unroll
            for (int kk = 0; kk < 4; ++kk) {
                const int cb = kk * 64 + (l >> 4) * 16;
                f16x8 a0 = *(const f16x8*)((char*)sA + swz2(rw + (l & 15), cb));
                f16x8 a1 = *(const f16x8*)((char*)sA + swz2(rw + 16 + (l & 15), cb));
                f16x8 b0 = *(const f16x8*)((char*)sB + swz2((l & 15), cb));
                acc0 = MFMA16(a0, b0, acc0);
                acc1 = MFMA16(a1, b0, acc1);
            }
            __syncthreads();
        }
        // keep rep's result alive so the compiler can't DCE non-final reps
        asm volatile("" :: "v"(acc0), "v"(acc1));
    }

    #pragma unroll
    for (int r = 0; r < 4; ++r) {
        const int col = c0 + (l & 15);
        Ob[(size_t)(rw + (l >> 4) * 4 + r) * HID + col]      = (f16)acc0[r];
        Ob[(size_t)(rw + 16 + (l >> 4) * 4 + r) * HID + col] = (f16)acc1[r];
    }
}

// ---------------- kernel B: flash attention (R2 + rep loop) ----------------
__global__ __launch_bounds__(512) void k_attn(
        const f16* __restrict__ Qw, const f16* __restrict__ Kw,
        const f16* __restrict__ Vw,
        const float* __restrict__ Kc, const float* __restrict__ Vc,
        const int* __restrict__ posp, f16* __restrict__ Ow) {

    __shared__ __align__(16) char smem[65536 + 1024];

    const int bh = blockIdx.x;
    const int b = bh >> 5, hh = bh & 31;
    const int tid = threadIdx.x, w = tid >> 6, l = tid & 63;
    const int pos = *posp;
    const int npure = pos >> 5;

    const float* Kb = Kc + (size_t)bh * (4096 * 128);
    const float* Vb = Vc + (size_t)bh * (4096 * 128);

    f16x8 qf[4];
    {
        const f16* qp = Qw + (size_t)(b * 16 + (l & 15)) * HID + hh * 128 + (l >> 4) * 8;
        #pragma unroll
        for (int kk = 0; kk < 4; ++kk) qf[kk] = *(const f16x8*)(qp + kk * 32);
    }

    f32x4 o[8];
    float m[4], lsum[4];

    f16* Pw = (f16*)smem + w * 640;

    const int start = (w * npure) >> 3;
    const int end   = ((w + 1) * npure) >> 3;

    for (int rep = 0; rep < ATTN_REPS; ++rep) {
        #pragma unroll
        for (int dt = 0; dt < 8; ++dt) o[dt] = (f32x4){};
        #pragma unroll
        for (int r = 0; r < 4; ++r) { m[r] = -3e38f; lsum[r] = 0.f; }

        for (int tau = start; tau < end; ++tau) {
            const int t0 = tau << 5;

            f16x8 kf[2][4];
            #pragma unroll
            for (int tn = 0; tn < 2; ++tn) {
                const float* kp = Kb + (size_t)(t0 + tn * 16 + (l & 15)) * 128 + (l >> 4) * 8;
                #pragma unroll
                for (int kk = 0; kk < 4; ++kk) {
                    float4 x = *(const float4*)(kp + kk * 32);
                    float4 y = *(const float4*)(kp + kk * 32 + 4);
                    kf[tn][kk] = cvt8(x, y);
                }
            }
            f32x4 sa[2] = {};
            #pragma unroll
            for (int tn = 0; tn < 2; ++tn)
                #pragma unroll
                for (int kk = 0; kk < 4; ++kk) sa[tn] = MFMA16(qf[kk], kf[tn][kk], sa[tn]);

            f16x8 vf[8];
            {
                const float* vp = Vb + (size_t)(t0 + (l >> 4) * 8) * 128 + (l & 15);
                #pragma unroll
                for (int dt = 0; dt < 8; ++dt)
                    #pragma unroll
                    for (int j = 0; j < 8; ++j) vf[dt][j] = (f16)vp[j * 128 + dt * 16];
            }

            float sc[2][4];
            #pragma unroll
            for (int tn = 0; tn < 2; ++tn)
                #pragma unroll
                for (int r = 0; r < 4; ++r) sc[tn][r] = sa[tn][r] * SCL;
            float vmax[4];
            #pragma unroll
            for (int r = 0; r < 4; ++r) vmax[r] = fmaxf(sc[0][r], sc[1][r]);
            #pragma unroll
            for (int d = 1; d < 16; d <<= 1)
                #pragma unroll
                for (int r = 0; r < 4; ++r) vmax[r] = fmaxf(vmax[r], __shfl_xor(vmax[r], d));
            float p[2][4], rs[4], fac[4];
            #pragma unroll
            for (int r = 0; r < 4; ++r) {
                const float mn = fmaxf(m[r], vmax[r]);
                fac[r] = exp2f(m[r] - mn);
                m[r] = mn;
                p[0][r] = exp2f(sc[0][r] - mn);
                p[1][r] = exp2f(sc[1][r] - mn);
                rs[r] = p[0][r] + p[1][r];
                lsum[r] *= fac[r];
            }
            #pragma unroll
            for (int d = 1; d < 16; d <<= 1)
                #pragma unroll
                for (int r = 0; r < 4; ++r) rs[r] += __shfl_xor(rs[r], d);
            #pragma unroll
            for (int r = 0; r < 4; ++r) lsum[r] += rs[r];
            #pragma unroll
            for (int dt = 0; dt < 8; ++dt)
                #pragma unroll
                for (int r = 0; r < 4; ++r) o[dt][r] *= fac[r];

            #pragma unroll
            for (int r = 0; r < 4; ++r) {
                const int s_ = (l >> 4) * 4 + r;
                Pw[s_ * 40 + (l & 15)]      = (f16)p[0][r];
                Pw[s_ * 40 + 16 + (l & 15)] = (f16)p[1][r];
            }
            asm volatile("s_waitcnt lgkmcnt(0)" ::: "memory");
            f16x8 pa = *(const f16x8*)(Pw + (l & 15) * 40 + (l >> 4) * 8);

            #pragma unroll
            for (int dt = 0; dt < 8; ++dt) o[dt] = MFMA16(pa, vf[dt], o[dt]);
        }

        // ---- boundary tiles: wave 7 only ----
        if (w == 7) {
            for (int t0 = npure << 5; t0 < pos + 16; t0 += 32) {
                f32x4 sa[2] = {};
                bool tnv[2];
                #pragma unroll
                for (int tn = 0; tn < 2; ++tn) {
                    tnv[tn] = (t0 + tn * 16 < pos + 16);
                    if (!tnv[tn]) continue;
                    const int trow = t0 + tn * 16 + (l & 15);
                    f16x8 kf[4];
                    if (trow < pos) {
                        const float* kp = Kb + (size_t)trow * 128 + (l >> 4) * 8;
                        #pragma unroll
                        for (int kk = 0; kk < 4; ++kk) {
                            float4 x = *(const float4*)(kp + kk * 32);
                            float4 y = *(const float4*)(kp + kk * 32 + 4);
                            kf[kk] = cvt8(x, y);
                        }
                    } else {
                        const int tt = trow - pos;
                        const int rr = tt < 15 ? tt : 15;
                        const f16* kp = Kw + (size_t)(b * 16 + rr) * HID + hh * 128 + (l >> 4) * 8;
                        #pragma unroll
                        for (int kk = 0; kk < 4; ++kk) kf[kk] = *(const f16x8*)(kp + kk * 32);
                    }
                    #pragma unroll
                    for (int kk = 0; kk < 4; ++kk) sa[tn] = MFMA16(qf[kk], kf[kk], sa[tn]);
                }

                float sc[2][4];
                #pragma unroll
                for (int tn = 0; tn < 2; ++tn) {
                    const int tg = t0 + tn * 16 + (l & 15);
                    #pragma unroll
                    for (int r = 0; r < 4; ++r) {
                        if (!tnv[tn]) { sc[tn][r] = -3e38f; continue; }
                        float v = sa[tn][r] * SCL;
                        if (tg >= pos) {
                            const int tt = tg - pos;
                            const int s_ = (l >> 4) * 4 + r;
                            if (tt > s_ || tt >= 16) v = -3e38f;
                        }
                        sc[tn][r] = v;
                    }
                }

                float vmax[4];
                #pragma unroll
                for (int r = 0; r < 4; ++r) vmax[r] = fmaxf(sc[0][r], sc[1][r]);
                #pragma unroll
                for (int d = 1; d < 16; d <<= 1)
                    #pragma unroll
                    for (int r = 0; r < 4; ++r) vmax[r] = fmaxf(vmax[r], __shfl_xor(vmax[r], d));
                float p[2][4], rs[4], fac[4];
                #pragma unroll
                for (int r = 0; r < 4; ++r) {
                    const float mn = fmaxf(m[r], vmax[r]);
                    fac[r] = exp2f(m[r] - mn);
                    m[r] = mn;
                    p[0][r] = sc[0][r] < -1e29f ? 0.f : exp2f(sc[0][r] - mn);
                    p[1][r] = sc[1][r] < -1e29f ? 0.f : exp2f(sc[1][r] - mn);
                    rs[r] = p[0][r] + p[1][r];
                    lsum[r] *= fac[r];
                }
                #pragma unroll
                for (int d = 1; d < 16; d <<= 1)
                    #pragma unroll
                    for (int r = 0; r < 4; ++r) rs[r] += __shfl_xor(rs[r], d);
                #pragma unroll
                for (int r = 0; r < 4; ++r) lsum[r] += rs[r];
                #pragma unroll
                for (int dt = 0; dt < 8; ++dt)
                    #pragma unroll
                    for (int r = 0; r < 4; ++r) o[dt][r] *= fac[r];

                #pragma unroll
                for (int r = 0; r < 4; ++r) {
                    const int s_ = (l >> 4) * 4 + r;
                    Pw[s_ * 40 + (l & 15)]      = (f16)p[0][r];
                    Pw[s_ * 40 + 16 + (l & 15)] = (f16)p[1][r];
                }
                asm volatile("s_waitcnt lgkmcnt(0)" ::: "memory");
                f16x8 pa = *(const f16x8*)(Pw + (l & 15) * 40 + (l >> 4) * 8);

                const int tb = t0 + (l >> 4) * 8;
                #pragma unroll
                for (int dt = 0; dt < 8; ++dt) {
                    f16x8 vf;
                    #pragma unroll
                    for (int j = 0; j < 8; ++j) {
                        const int t = tb + j;
                        if (t < pos) {
                            vf[j] = (f16)Vb[(size_t)t * 128 + dt * 16 + (l & 15)];
                        } else {
                            const int rr = (t - pos < 15) ? (t - pos) : 15;
                            vf[j] = Vw[(size_t)(b * 16 + rr) * HID + hh * 128 + dt * 16 + (l & 15)];
                        }
                    }
                    o[dt] = MFMA16(pa, vf, o[dt]);
                }
            }
        }
        // keep rep's state alive so non-final reps aren't DCE'd
        #pragma unroll
        for (int dt = 0; dt < 8; ++dt) asm volatile("" :: "v"(o[dt]));
        asm volatile("" :: "v"(m[0]), "v"(m[3]), "v"(lsum[0]), "v"(lsum[3]));
    }

    // ---- merge 8 per-wave partials ----
    __syncthreads();
    float* Osh = (float*)smem;                 // [8][16][128]
    float* Msh = (float*)(smem + 65536);       // [8][16]
    float* Lsh = Msh + 128;
    #pragma unroll
    for (int dt = 0; dt < 8; ++dt)
        #pragma unroll
        for (int r = 0; r < 4; ++r)
            Osh[w * 2048 + ((l >> 4) * 4 + r) * 128 + dt * 16 + (l & 15)] = o[dt][r];
    if ((l & 15) == 0) {
        #pragma unroll
        for (int r = 0; r < 4; ++r) {
            Msh[w * 16 + (l >> 4) * 4 + r] = m[r];
            Lsh[w * 16 + (l >> 4) * 4 + r] = lsum[r];
        }
    }
    __syncthreads();
    {
        const int s_ = tid >> 5;           // 0..15
        const int d_ = (tid & 31) * 4;     // 0..124
        float M = -3e38f;
        #pragma unroll
        for (int ww = 0; ww < 8; ++ww) M = fmaxf(M, Msh[ww * 16 + s_]);
        float L = 0.f;
        f32x4 oa = {};
        #pragma unroll
        for (int ww = 0; ww < 8; ++ww) {
            const float e = exp2f(Msh[ww * 16 + s_] - M);
            L += e * Lsh[ww * 16 + s_];
            f32x4 v = *(const f32x4*)(Osh + ww * 2048 + s_ * 128 + d_);
            #pragma unroll
            for (int r = 0; r < 4; ++r) oa[r] += e * v[r];
        }
        const float inv = 1.f / L;
        f16x4 res = {(f16)(oa[0] * inv), (f16)(oa[1] * inv),
                     (f16)(oa[2] * inv), (f16)(oa[3] * inv)};
        *(f16x4*)(Ow + (size_t)(b * 16 + s_) * HID + hh * 128 + d_) = res;
    }
}

// ---------------- kernel C: output projection (unchanged, x1) ----------------
__global__ __launch_bounds__(256) void k_oproj(
        const f16* __restrict__ Oa, const float* __restrict__ Wo,
        float* __restrict__ out) {
    const int c0 = blockIdx.x * 16;

    __shared__ __align__(16) f16 sA[128 * 128];
    __shared__ __align__(16) f16 sB[16 * 128];

    const int tid = threadIdx.x;
    const int w = tid >> 6, l = tid & 63;
    const int rw = w * 32;
    const int ar = tid >> 4;
    const int ac = (tid & 15) * 8;

    f32x4 acc0 = {}, acc1 = {};

    float4 wx, wy;
    f16x8 hreg[8];
    {
        const float* wp = Wo + (size_t)(c0 + ar) * HID + ac;
        wx = *(const float4*)wp; wy = *(const float4*)(wp + 4);
        #pragma unroll
        for (int c = 0; c < 8; ++c)
            hreg[c] = *(const f16x8*)(Oa + (size_t)(c * 16 + ar) * HID + ac);
    }

    for (int ks = 0; ks < 32; ++ks) {
        #pragma unroll
        for (int c = 0; c < 8; ++c)
            *(f16x8*)((char*)sA + swz2(c * 16 + ar, ac * 2)) = hreg[c];
        *(f16x8*)((char*)sB + swz2(ar, ac * 2)) = cvt8(wx, wy);
        __syncthreads();
        if (ks < 31) {
            const int k0 = (ks + 1) * 128;
            const float* wp = Wo + (size_t)(c0 + ar) * HID + k0 + ac;
            wx = *(const float4*)wp; wy = *(const float4*)(wp + 4);
            #pragma unroll
            for (int c = 0; c < 8; ++c)
                hreg[c] = *(const f16x8*)(Oa + (size_t)(c * 16 + ar) * HID + k0 + ac);
        }
        #pragma unroll
        for (int kk = 0; kk < 4; ++kk) {
            const int cb = kk * 64 + (l >> 4) * 16;
            f16x8 a0 = *(const f16x8*)((char*)sA + swz2(rw + (l & 15), cb));
            f16x8 a1 = *(const f16x8*)((char*)sA + swz2(rw + 16 + (l & 15), cb));
            f16x8 b0 = *(const f16x8*)((char*)sB + swz2((l & 15), cb));
            acc0 = MFMA16(a0, b0, acc0);
            acc1 = MFMA16(a1, b0, acc1);
        }
        __syncthreads();
    }
    #pragma unroll
    for (int r = 0; r < 4; ++r) {
        const int col = c0 + (l & 15);
        out[(size_t)(rw + (l >> 4) * 4 + r) * HID + col]      = acc0[r];
        out[(size_t)(rw + 16 + (l >> 4) * 4 + r) * HID + col] = acc1[r];
    }
}

extern "C" void kernel_launch(void* const* d_in, const int* in_sizes, int n_in,
                              void* d_out, int out_size, void* d_ws, size_t ws_size,
                              hipStream_t stream) {
    const float* h  = (const float*)d_in[0];
    const float* Wq = (const float*)d_in[1];
    const float* Wk = (const float*)d_in[2];
    const float* Wv = (const float*)d_in[3];
    const float* Wo = (const float*)d_in[4];
    const float* Kc = (const float*)d_in[5];
    const float* Vc = (const float*)d_in[6];
    const int* pos  = (const int*)d_in[7];
    float* out = (float*)d_out;

    f16* hws = (f16*)d_ws;            // 128*4096 f16 = 1 MB
    f16* Qw  = hws + ROWS * HID;
    f16* Kw  = Qw + ROWS * HID;
    f16* Vw  = Kw + ROWS * HID;
    f16* Ow  = Vw + ROWS * HID;

    k_cvt<<<256, 256, 0, stream>>>(h, hws);
    k_proj<<<768, 256, 0, stream>>>(hws, Wq, Wk, Wv, Qw, Kw, Vw);
    k_attn<<<256, 512, 0, stream>>>(Qw, Kw, Vw, Kc, Vc, pos, Ow);
    k_oproj<<<256, 256, 0, stream>>>(Ow, Wo, out);
}

// Round 6
// 310.310 us; speedup vs baseline: 3.8360x; 3.8360x over previous
//
#include <hip/hip_runtime.h>

typedef _Float16 f16;
typedef _Float16 f16x8 __attribute__((ext_vector_type(8)));
typedef _Float16 f16x4 __attribute__((ext_vector_type(4)));
typedef _Float16 f16x2 __attribute__((ext_vector_type(2)));
typedef float f32x4 __attribute__((ext_vector_type(4)));
typedef float f32x2 __attribute__((ext_vector_type(2)));

#define MFMA16(a, b, c) __builtin_amdgcn_mfma_f32_16x16x32_f16(a, b, c, 0, 0, 0)

#define HID 4096
#define ROWS 128      // B*S
#define SCL 0.12751743f  // (1/sqrt(128)) * log2(e)

__device__ __forceinline__ f16x8 cvt8(float4 x, float4 y) {
    f16x8 v = {(f16)x.x, (f16)x.y, (f16)x.z, (f16)x.w,
               (f16)y.x, (f16)y.y, (f16)y.z, (f16)y.w};
    return v;
}

// XOR swizzle for a tile with 128 f16 (256 B) row pitch
__device__ __forceinline__ int swz2(int row, int cb) {
    return row * 256 + (cb ^ ((row & 7) << 4));
}

// ---------------- kernel 0: h fp32 -> f16 ----------------
__global__ void k_cvt(const float* __restrict__ src, f16* __restrict__ dst) {
    const int i = blockIdx.x * blockDim.x + threadIdx.x;
    const float4* s4 = (const float4*)src + (size_t)i * 2;
    float4 x = s4[0], y = s4[1];
    *((f16x8*)dst + i) = cvt8(x, y);
}

// ---------------- kernel A: fused QKV projection ----------------
// LDS-free, barrier-free streaming GEMM. B-fragments (W rows) and
// A-fragments (h rows) loaded directly from memory in MFMA layout
// (same pattern k_attn uses for K). One-iter register prefetch.
// 768 blocks x 4 waves; W lines fetched exactly once from HBM; h is
// L2-resident. Measured R5: LDS version was latency-bound (25% HBM,
// MfmaUtil 11%, 7.5e7 LDS bank-conflict cycles) at ~51us.
__global__ __launch_bounds__(256, 3) void k_proj(
        const f16* __restrict__ hb,
        const float* __restrict__ Wq, const float* __restrict__ Wk,
        const float* __restrict__ Wv,
        f16* __restrict__ Qw, f16* __restrict__ Kw, f16* __restrict__ Vw) {
    const int mat = blockIdx.x >> 8;     // 0..2
    const int ct  = blockIdx.x & 255;    // 256 col tiles of 16
    const float* __restrict__ W = (mat == 0) ? Wq : (mat == 1) ? Wk : Wv;
    f16* __restrict__ Ob = (mat == 0) ? Qw : (mat == 1) ? Kw : Vw;
    const int c0 = ct * 16;

    const int tid = threadIdx.x;
    const int w = tid >> 6, l = tid & 63;
    const int r0 = w * 32;               // this wave's 32 output rows

    // per-lane fragment base pointers (16B chunk per lane)
    const float* wp  = W  + (size_t)(c0 + (l & 15)) * HID + ((l >> 4) * 8);
    const f16*   hp0 = hb + (size_t)(r0 + (l & 15)) * HID + ((l >> 4) * 8);
    const f16*   hp1 = hp0 + (size_t)16 * HID;

    f32x4 acc0 = {}, acc1 = {};

    float4 wf[4][2];     // current W   [kk][lo/hi]
    f16x8  ha[2][4];     // current h   [m][kk]

    #pragma unroll
    for (int kk = 0; kk < 4; ++kk) {
        wf[kk][0] = *(const float4*)(wp + kk * 32);
        wf[kk][1] = *(const float4*)(wp + kk * 32 + 4);
        ha[0][kk] = *(const f16x8*)(hp0 + kk * 32);
        ha[1][kk] = *(const f16x8*)(hp1 + kk * 32);
    }

    for (int ks = 0; ks < 32; ++ks) {
        float4 nwf[4][2];
        f16x8  nha[2][4];
        if (ks < 31) {
            const int k0 = (ks + 1) * 128;
            #pragma unroll
            for (int kk = 0; kk < 4; ++kk) {
                nwf[kk][0] = *(const float4*)(wp + k0 + kk * 32);
                nwf[kk][1] = *(const float4*)(wp + k0 + kk * 32 + 4);
                nha[0][kk] = *(const f16x8*)(hp0 + k0 + kk * 32);
                nha[1][kk] = *(const f16x8*)(hp1 + k0 + kk * 32);
            }
        }
        #pragma unroll
        for (int kk = 0; kk < 4; ++kk) {
            const f16x8 bw = cvt8(wf[kk][0], wf[kk][1]);
            acc0 = MFMA16(ha[0][kk], bw, acc0);
            acc1 = MFMA16(ha[1][kk], bw, acc1);
        }
        if (ks < 31) {
            #pragma unroll
            for (int kk = 0; kk < 4; ++kk) {
                wf[kk][0] = nwf[kk][0]; wf[kk][1] = nwf[kk][1];
                ha[0][kk] = nha[0][kk]; ha[1][kk] = nha[1][kk];
            }
        }
    }

    #pragma unroll
    for (int r = 0; r < 4; ++r) {
        const int row = r0 + (l >> 4) * 4 + r;
        const int col = c0 + (l & 15);
        Ob[(size_t)row * HID + col]        = (f16)acc0[r];
        Ob[(size_t)(row + 16) * HID + col] = (f16)acc1[r];
    }
}

// ---------------- kernel B: flash attention, 1 block per (b,h), 8 waves ----------------
// (unchanged from R2 — measured at the 86us KV HBM floor in R5)
__global__ __launch_bounds__(512) void k_attn(
        const f16* __restrict__ Qw, const f16* __restrict__ Kw,
        const f16* __restrict__ Vw,
        const float* __restrict__ Kc, const float* __restrict__ Vc,
        const int* __restrict__ posp, f16* __restrict__ Ow) {

    __shared__ __align__(16) char smem[65536 + 1024];

    const int bh = blockIdx.x;
    const int b = bh >> 5, hh = bh & 31;
    const int tid = threadIdx.x, w = tid >> 6, l = tid & 63;
    const int pos = *posp;
    const int npure = pos >> 5;

    const float* Kb = Kc + (size_t)bh * (4096 * 128);
    const float* Vb = Vc + (size_t)bh * (4096 * 128);

    f16x8 qf[4];
    {
        const f16* qp = Qw + (size_t)(b * 16 + (l & 15)) * HID + hh * 128 + (l >> 4) * 8;
        #pragma unroll
        for (int kk = 0; kk < 4; ++kk) qf[kk] = *(const f16x8*)(qp + kk * 32);
    }

    f32x4 o[8] = {};
    float m[4], lsum[4];
    #pragma unroll
    for (int r = 0; r < 4; ++r) { m[r] = -3e38f; lsum[r] = 0.f; }

    f16* Pw = (f16*)smem + w * 640;

    const int start = (w * npure) >> 3;
    const int end   = ((w + 1) * npure) >> 3;
    for (int tau = start; tau < end; ++tau) {
        const int t0 = tau << 5;

        f16x8 kf[2][4];
        #pragma unroll
        for (int tn = 0; tn < 2; ++tn) {
            const float* kp = Kb + (size_t)(t0 + tn * 16 + (l & 15)) * 128 + (l >> 4) * 8;
            #pragma unroll
            for (int kk = 0; kk < 4; ++kk) {
                float4 x = *(const float4*)(kp + kk * 32);
                float4 y = *(const float4*)(kp + kk * 32 + 4);
                kf[tn][kk] = cvt8(x, y);
            }
        }
        f32x4 sa[2] = {};
        #pragma unroll
        for (int tn = 0; tn < 2; ++tn)
            #pragma unroll
            for (int kk = 0; kk < 4; ++kk) sa[tn] = MFMA16(qf[kk], kf[tn][kk], sa[tn]);

        f16x8 vf[8];
        {
            const float* vp = Vb + (size_t)(t0 + (l >> 4) * 8) * 128 + (l & 15);
            #pragma unroll
            for (int dt = 0; dt < 8; ++dt)
                #pragma unroll
                for (int j = 0; j < 8; ++j) vf[dt][j] = (f16)vp[j * 128 + dt * 16];
        }

        float sc[2][4];
        #pragma unroll
        for (int tn = 0; tn < 2; ++tn)
            #pragma unroll
            for (int r = 0; r < 4; ++r) sc[tn][r] = sa[tn][r] * SCL;
        float vmax[4];
        #pragma unroll
        for (int r = 0; r < 4; ++r) vmax[r] = fmaxf(sc[0][r], sc[1][r]);
        #pragma unroll
        for (int d = 1; d < 16; d <<= 1)
            #pragma unroll
            for (int r = 0; r < 4; ++r) vmax[r] = fmaxf(vmax[r], __shfl_xor(vmax[r], d));
        float p[2][4], rs[4], fac[4];
        #pragma unroll
        for (int r = 0; r < 4; ++r) {
            const float mn = fmaxf(m[r], vmax[r]);
            fac[r] = exp2f(m[r] - mn);
            m[r] = mn;
            p[0][r] = exp2f(sc[0][r] - mn);
            p[1][r] = exp2f(sc[1][r] - mn);
            rs[r] = p[0][r] + p[1][r];
            lsum[r] *= fac[r];
        }
        #pragma unroll
        for (int d = 1; d < 16; d <<= 1)
            #pragma unroll
            for (int r = 0; r < 4; ++r) rs[r] += __shfl_xor(rs[r], d);
        #pragma unroll
        for (int r = 0; r < 4; ++r) lsum[r] += rs[r];
        #pragma unroll
        for (int dt = 0; dt < 8; ++dt)
            #pragma unroll
            for (int r = 0; r < 4; ++r) o[dt][r] *= fac[r];

        #pragma unroll
        for (int r = 0; r < 4; ++r) {
            const int s_ = (l >> 4) * 4 + r;
            Pw[s_ * 40 + (l & 15)]      = (f16)p[0][r];
            Pw[s_ * 40 + 16 + (l & 15)] = (f16)p[1][r];
        }
        asm volatile("s_waitcnt lgkmcnt(0)" ::: "memory");
        f16x8 pa = *(const f16x8*)(Pw + (l & 15) * 40 + (l >> 4) * 8);

        #pragma unroll
        for (int dt = 0; dt < 8; ++dt) o[dt] = MFMA16(pa, vf[dt], o[dt]);
    }

    // ---- boundary tiles (cache tail + 16 new rows): wave 7 only ----
    if (w == 7) {
        for (int t0 = npure << 5; t0 < pos + 16; t0 += 32) {
            f32x4 sa[2] = {};
            bool tnv[2];
            #pragma unroll
            for (int tn = 0; tn < 2; ++tn) {
                tnv[tn] = (t0 + tn * 16 < pos + 16);
                if (!tnv[tn]) continue;
                const int trow = t0 + tn * 16 + (l & 15);
                f16x8 kf[4];
                if (trow < pos) {
                    const float* kp = Kb + (size_t)trow * 128 + (l >> 4) * 8;
                    #pragma unroll
                    for (int kk = 0; kk < 4; ++kk) {
                        float4 x = *(const float4*)(kp + kk * 32);
                        float4 y = *(const float4*)(kp + kk * 32 + 4);
                        kf[kk] = cvt8(x, y);
                    }
                } else {
                    const int tt = trow - pos;
                    const int rr = tt < 15 ? tt : 15;
                    const f16* kp = Kw + (size_t)(b * 16 + rr) * HID + hh * 128 + (l >> 4) * 8;
                    #pragma unroll
                    for (int kk = 0; kk < 4; ++kk) kf[kk] = *(const f16x8*)(kp + kk * 32);
                }
                #pragma unroll
                for (int kk = 0; kk < 4; ++kk) sa[tn] = MFMA16(qf[kk], kf[kk], sa[tn]);
            }

            float sc[2][4];
            #pragma unroll
            for (int tn = 0; tn < 2; ++tn) {
                const int tg = t0 + tn * 16 + (l & 15);
                #pragma unroll
                for (int r = 0; r < 4; ++r) {
                    if (!tnv[tn]) { sc[tn][r] = -3e38f; continue; }
                    float v = sa[tn][r] * SCL;
                    if (tg >= pos) {
                        const int tt = tg - pos;
                        const int s_ = (l >> 4) * 4 + r;
                        if (tt > s_ || tt >= 16) v = -3e38f;
                    }
                    sc[tn][r] = v;
                }
            }

            float vmax[4];
            #pragma unroll
            for (int r = 0; r < 4; ++r) vmax[r] = fmaxf(sc[0][r], sc[1][r]);
            #pragma unroll
            for (int d = 1; d < 16; d <<= 1)
                #pragma unroll
                for (int r = 0; r < 4; ++r) vmax[r] = fmaxf(vmax[r], __shfl_xor(vmax[r], d));
            float p[2][4], rs[4], fac[4];
            #pragma unroll
            for (int r = 0; r < 4; ++r) {
                const float mn = fmaxf(m[r], vmax[r]);
                fac[r] = exp2f(m[r] - mn);
                m[r] = mn;
                p[0][r] = sc[0][r] < -1e29f ? 0.f : exp2f(sc[0][r] - mn);
                p[1][r] = sc[1][r] < -1e29f ? 0.f : exp2f(sc[1][r] - mn);
                rs[r] = p[0][r] + p[1][r];
                lsum[r] *= fac[r];
            }
            #pragma unroll
            for (int d = 1; d < 16; d <<= 1)
                #pragma unroll
                for (int r = 0; r < 4; ++r) rs[r] += __shfl_xor(rs[r], d);
            #pragma unroll
            for (int r = 0; r < 4; ++r) lsum[r] += rs[r];
            #pragma unroll
            for (int dt = 0; dt < 8; ++dt)
                #pragma unroll
                for (int r = 0; r < 4; ++r) o[dt][r] *= fac[r];

            #pragma unroll
            for (int r = 0; r < 4; ++r) {
                const int s_ = (l >> 4) * 4 + r;
                Pw[s_ * 40 + (l & 15)]      = (f16)p[0][r];
                Pw[s_ * 40 + 16 + (l & 15)] = (f16)p[1][r];
            }
            asm volatile("s_waitcnt lgkmcnt(0)" ::: "memory");
            f16x8 pa = *(const f16x8*)(Pw + (l & 15) * 40 + (l >> 4) * 8);

            const int tb = t0 + (l >> 4) * 8;
            #pragma unroll
            for (int dt = 0; dt < 8; ++dt) {
                f16x8 vf;
                #pragma unroll
                for (int j = 0; j < 8; ++j) {
                    const int t = tb + j;
                    if (t < pos) {
                        vf[j] = (f16)Vb[(size_t)t * 128 + dt * 16 + (l & 15)];
                    } else {
                        const int rr = (t - pos < 15) ? (t - pos) : 15;
                        vf[j] = Vw[(size_t)(b * 16 + rr) * HID + hh * 128 + dt * 16 + (l & 15)];
                    }
                }
                o[dt] = MFMA16(pa, vf, o[dt]);
            }
        }
    }

    // ---- merge 8 per-wave partials ----
    __syncthreads();
    float* Osh = (float*)smem;                 // [8][16][128]
    float* Msh = (float*)(smem + 65536);       // [8][16]
    float* Lsh = Msh + 128;
    #pragma unroll
    for (int dt = 0; dt < 8; ++dt)
        #pragma unroll
        for (int r = 0; r < 4; ++r)
            Osh[w * 2048 + ((l >> 4) * 4 + r) * 128 + dt * 16 + (l & 15)] = o[dt][r];
    if ((l & 15) == 0) {
        #pragma unroll
        for (int r = 0; r < 4; ++r) {
            Msh[w * 16 + (l >> 4) * 4 + r] = m[r];
            Lsh[w * 16 + (l >> 4) * 4 + r] = lsum[r];
        }
    }
    __syncthreads();
    {
        const int s_ = tid >> 5;           // 0..15
        const int d_ = (tid & 31) * 4;     // 0..124
        float M = -3e38f;
        #pragma unroll
        for (int ww = 0; ww < 8; ++ww) M = fmaxf(M, Msh[ww * 16 + s_]);
        float L = 0.f;
        f32x4 oa = {};
        #pragma unroll
        for (int ww = 0; ww < 8; ++ww) {
            const float e = exp2f(Msh[ww * 16 + s_] - M);
            L += e * Lsh[ww * 16 + s_];
            f32x4 v = *(const f32x4*)(Osh + ww * 2048 + s_ * 128 + d_);
            #pragma unroll
            for (int r = 0; r < 4; ++r) oa[r] += e * v[r];
        }
        const float inv = 1.f / L;
        f16x4 res = {(f16)(oa[0] * inv), (f16)(oa[1] * inv),
                     (f16)(oa[2] * inv), (f16)(oa[3] * inv)};
        *(f16x4*)(Ow + (size_t)(b * 16 + s_) * HID + hh * 128 + d_) = res;
    }
}

// ---------------- kernel C: output projection (unchanged from R2) ----------------
__global__ __launch_bounds__(256) void k_oproj(
        const f16* __restrict__ Oa, const float* __restrict__ Wo,
        float* __restrict__ out) {
    const int c0 = blockIdx.x * 16;

    __shared__ __align__(16) f16 sA[128 * 128];
    __shared__ __align__(16) f16 sB[16 * 128];

    const int tid = threadIdx.x;
    const int w = tid >> 6, l = tid & 63;
    const int rw = w * 32;
    const int ar = tid >> 4;
    const int ac = (tid & 15) * 8;

    f32x4 acc0 = {}, acc1 = {};

    float4 wx, wy;
    f16x8 hreg[8];
    {
        const float* wp = Wo + (size_t)(c0 + ar) * HID + ac;
        wx = *(const float4*)wp; wy = *(const float4*)(wp + 4);
        #pragma unroll
        for (int c = 0; c < 8; ++c)
            hreg[c] = *(const f16x8*)(Oa + (size_t)(c * 16 + ar) * HID + ac);
    }

    for (int ks = 0; ks < 32; ++ks) {
        #pragma unroll
        for (int c = 0; c < 8; ++c)
            *(f16x8*)((char*)sA + swz2(c * 16 + ar, ac * 2)) = hreg[c];
        *(f16x8*)((char*)sB + swz2(ar, ac * 2)) = cvt8(wx, wy);
        __syncthreads();
        if (ks < 31) {
            const int k0 = (ks + 1) * 128;
            const float* wp = Wo + (size_t)(c0 + ar) * HID + k0 + ac;
            wx = *(const float4*)wp; wy = *(const float4*)(wp + 4);
            #pragma unroll
            for (int c = 0; c < 8; ++c)
                hreg[c] = *(const f16x8*)(Oa + (size_t)(c * 16 + ar) * HID + k0 + ac);
        }
        #pragma unroll
        for (int kk = 0; kk < 4; ++kk) {
            const int cb = kk * 64 + (l >> 4) * 16;
            f16x8 a0 = *(const f16x8*)((char*)sA + swz2(rw + (l & 15), cb));
            f16x8 a1 = *(const f16x8*)((char*)sA + swz2(rw + 16 + (l & 15), cb));
            f16x8 b0 = *(const f16x8*)((char*)sB + swz2((l & 15), cb));
            acc0 = MFMA16(a0, b0, acc0);
            acc1 = MFMA16(a1, b0, acc1);
        }
        __syncthreads();
    }
    #pragma unroll
    for (int r = 0; r < 4; ++r) {
        const int col = c0 + (l & 15);
        out[(size_t)(rw + (l >> 4) * 4 + r) * HID + col]      = acc0[r];
        out[(size_t)(rw + 16 + (l >> 4) * 4 + r) * HID + col] = acc1[r];
    }
}

extern "C" void kernel_launch(void* const* d_in, const int* in_sizes, int n_in,
                              void* d_out, int out_size, void* d_ws, size_t ws_size,
                              hipStream_t stream) {
    const float* h  = (const float*)d_in[0];
    const float* Wq = (const float*)d_in[1];
    const float* Wk = (const float*)d_in[2];
    const float* Wv = (const float*)d_in[3];
    const float* Wo = (const float*)d_in[4];
    const float* Kc = (const float*)d_in[5];
    const float* Vc = (const float*)d_in[6];
    const int* pos  = (const int*)d_in[7];
    float* out = (float*)d_out;

    f16* hws = (f16*)d_ws;            // 128*4096 f16 = 1 MB
    f16* Qw  = hws + ROWS * HID;
    f16* Kw  = Qw + ROWS * HID;
    f16* Vw  = Kw + ROWS * HID;
    f16* Ow  = Vw + ROWS * HID;

    k_cvt<<<256, 256, 0, stream>>>(h, hws);
    k_proj<<<768, 256, 0, stream>>>(hws, Wq, Wk, Wv, Qw, Kw, Vw);
    k_attn<<<256, 512, 0, stream>>>(Qw, Kw, Vw, Kc, Vc, pos, Ow);
    k_oproj<<<256, 256, 0, stream>>>(Ow, Wo, out);
}

// Round 7
// 270.783 us; speedup vs baseline: 4.3960x; 1.1460x over previous
//
#include <hip/hip_runtime.h>

typedef _Float16 f16;
typedef _Float16 f16x8 __attribute__((ext_vector_type(8)));
typedef _Float16 f16x4 __attribute__((ext_vector_type(4)));
typedef _Float16 f16x2 __attribute__((ext_vector_type(2)));
typedef float f32x4 __attribute__((ext_vector_type(4)));
typedef float f32x2 __attribute__((ext_vector_type(2)));

#define MFMA16(a, b, c) __builtin_amdgcn_mfma_f32_16x16x32_f16(a, b, c, 0, 0, 0)

#define HID 4096
#define ROWS 128      // B*S
#define SCL 0.12751743f  // (1/sqrt(128)) * log2(e)

__device__ __forceinline__ f16x8 cvt8(float4 x, float4 y) {
    f16x8 v = {(f16)x.x, (f16)x.y, (f16)x.z, (f16)x.w,
               (f16)y.x, (f16)y.y, (f16)y.z, (f16)y.w};
    return v;
}

// XOR swizzle for a tile with 128 f16 (256 B) row pitch (attn P-transpose etc.)
__device__ __forceinline__ int swz2(int row, int cb) {
    return row * 256 + (cb ^ ((row & 7) << 4));
}

// async global->LDS, 16B per lane; dest is wave-uniform base + lane*16 (HW rule)
__device__ __forceinline__ void gload16(const void* g, void* s) {
    __builtin_amdgcn_global_load_lds(
        (const __attribute__((address_space(1))) void*)g,
        (__attribute__((address_space(3))) void*)s, 16, 0, 0);
}

// ---------------- kernel 0: h fp32 -> f16 ----------------
__global__ void k_cvt(const float* __restrict__ src, f16* __restrict__ dst) {
    const int i = blockIdx.x * blockDim.x + threadIdx.x;
    const float4* s4 = (const float4*)src + (size_t)i * 2;
    float4 x = s4[0], y = s4[1];
    *((f16x8*)dst + i) = cvt8(x, y);
}

// ======================================================================
// Projection GEMM core (shared by k_proj / k_oproj):
//  - W tile (16 rows x 128 fp32 = 8 KB) double-buffered in LDS via
//    global_load_lds: linear LDS dest, INVERSE-swizzled global source,
//    swizzled ds_read (rule #21) -> conflict-free reads, coalesced src.
//  - A (f16 activations, L2-hot) loaded per-lane in MFMA layout with
//    1-iteration register prefetch.
//  - one __syncthreads per K-step (drains gload_lds queue, m97 pattern).
// ======================================================================

// stage W[c0+row][k0 + 0..127] (fp32) into lds tile (linear [16][128])
__device__ __forceinline__ void stage_w(const float* __restrict__ Wrow0k,
                                        float* __restrict__ lds, int tid) {
    const int w = tid >> 6, l = tid & 63;
    #pragma unroll
    for (int i = 0; i < 2; ++i) {
        const int g    = w * 2048 + i * 1024 + l * 16;   // byte idx in 8KB tile
        const int row  = g >> 9;                         // 512 B per row
        const int colb = (g & 511) ^ ((row & 7) << 4);   // inverse swizzle
        gload16((const char*)(Wrow0k + (size_t)row * HID) + colb,
                (char*)lds + w * 2048 + i * 1024);
    }
}

__device__ __forceinline__ void proj_core(
        const f16* __restrict__ Ab,   // activation base (128 x HID f16)
        const float* __restrict__ W,  // weight, row = output col, c0 pre-offset NOT applied
        int c0, int tid,
        float* __restrict__ sW,       // LDS, 2 x 2048 floats
        f32x4& acc0, f32x4& acc1) {
    const int w = tid >> 6, l = tid & 63;
    const int r0 = w * 32;

    const f16* hp0 = Ab + (size_t)(r0 + (l & 15)) * HID + ((l >> 4) * 8);
    const f16* hp1 = hp0 + (size_t)16 * HID;
    const float* Wc = W + (size_t)c0 * HID;

    const int rrow = l & 15;
    const int rswz = (rrow & 7) << 4;
    const char* sWr0 = (const char*)sW + rrow * 512;          // buf 0
    const char* sWr1 = (const char*)sW + 8192 + rrow * 512;   // buf 1

    f16x8 ha[2][4], nha[2][4];

    // prologue: stage k=0 into buf0, load h(k=0)
    stage_w(Wc, sW, tid);
    #pragma unroll
    for (int kk = 0; kk < 4; ++kk) {
        ha[0][kk] = *(const f16x8*)(hp0 + kk * 32);
        ha[1][kk] = *(const f16x8*)(hp1 + kk * 32);
    }
    __syncthreads();

    for (int ks = 0; ks < 32; ++ks) {
        const int buf = ks & 1;
        // async-stage next W tile + prefetch next h frags
        if (ks < 31) {
            const int kn = (ks + 1) * 128;
            stage_w(Wc + kn, sW + (buf ^ 1) * 2048, tid);
            #pragma unroll
            for (int kk = 0; kk < 4; ++kk) {
                nha[0][kk] = *(const f16x8*)(hp0 + kn + kk * 32);
                nha[1][kk] = *(const f16x8*)(hp1 + kn + kk * 32);
            }
        }
        // compute on current buffer
        const char* sWr = buf ? sWr1 : sWr0;
        #pragma unroll
        for (int kk = 0; kk < 4; ++kk) {
            const int cb = kk * 128 + (l >> 4) * 32;
            float4 wa = *(const float4*)(sWr + ((cb)      ^ rswz));
            float4 wb = *(const float4*)(sWr + ((cb + 16) ^ rswz));
            const f16x8 bw = cvt8(wa, wb);
            acc0 = MFMA16(ha[0][kk], bw, acc0);
            acc1 = MFMA16(ha[1][kk], bw, acc1);
        }
        if (ks < 31) {
            #pragma unroll
            for (int kk = 0; kk < 4; ++kk) {
                ha[0][kk] = nha[0][kk];
                ha[1][kk] = nha[1][kk];
            }
        }
        __syncthreads();   // drains gload_lds + nha loads; next buf ready
    }
}

// ---------------- kernel A: fused QKV projection ----------------
__global__ __launch_bounds__(256) void k_proj(
        const f16* __restrict__ hb,
        const float* __restrict__ Wq, const float* __restrict__ Wk,
        const float* __restrict__ Wv,
        f16* __restrict__ Qw, f16* __restrict__ Kw, f16* __restrict__ Vw) {
    const int mat = blockIdx.x >> 8;
    const int ct  = blockIdx.x & 255;
    const float* __restrict__ W = (mat == 0) ? Wq : (mat == 1) ? Wk : Wv;
    f16* __restrict__ Ob = (mat == 0) ? Qw : (mat == 1) ? Kw : Vw;
    const int c0 = ct * 16;

    __shared__ __align__(16) float sW[2 * 2048];   // 16 KB double-buffered W tile

    const int tid = threadIdx.x;
    const int w = tid >> 6, l = tid & 63;

    f32x4 acc0 = {}, acc1 = {};
    proj_core(hb, W, c0, tid, sW, acc0, acc1);

    #pragma unroll
    for (int r = 0; r < 4; ++r) {
        const int row = w * 32 + (l >> 4) * 4 + r;
        const int col = c0 + (l & 15);
        Ob[(size_t)row * HID + col]        = (f16)acc0[r];
        Ob[(size_t)(row + 16) * HID + col] = (f16)acc1[r];
    }
}

// ---------------- kernel C: output projection (same core, fp32 out) ----------------
__global__ __launch_bounds__(256) void k_oproj(
        const f16* __restrict__ Oa, const float* __restrict__ Wo,
        float* __restrict__ out) {
    const int c0 = blockIdx.x * 16;

    __shared__ __align__(16) float sW[2 * 2048];

    const int tid = threadIdx.x;
    const int w = tid >> 6, l = tid & 63;

    f32x4 acc0 = {}, acc1 = {};
    proj_core(Oa, Wo, c0, tid, sW, acc0, acc1);

    #pragma unroll
    for (int r = 0; r < 4; ++r) {
        const int row = w * 32 + (l >> 4) * 4 + r;
        const int col = c0 + (l & 15);
        out[(size_t)row * HID + col]        = acc0[r];
        out[(size_t)(row + 16) * HID + col] = acc1[r];
    }
}

// ---------------- kernel B: flash attention, 1 block per (b,h), 8 waves ----------------
// (unchanged from R2 — measured at the 86us KV HBM floor in R5)
__global__ __launch_bounds__(512) void k_attn(
        const f16* __restrict__ Qw, const f16* __restrict__ Kw,
        const f16* __restrict__ Vw,
        const float* __restrict__ Kc, const float* __restrict__ Vc,
        const int* __restrict__ posp, f16* __restrict__ Ow) {

    __shared__ __align__(16) char smem[65536 + 1024];

    const int bh = blockIdx.x;
    const int b = bh >> 5, hh = bh & 31;
    const int tid = threadIdx.x, w = tid >> 6, l = tid & 63;
    const int pos = *posp;
    const int npure = pos >> 5;

    const float* Kb = Kc + (size_t)bh * (4096 * 128);
    const float* Vb = Vc + (size_t)bh * (4096 * 128);

    f16x8 qf[4];
    {
        const f16* qp = Qw + (size_t)(b * 16 + (l & 15)) * HID + hh * 128 + (l >> 4) * 8;
        #pragma unroll
        for (int kk = 0; kk < 4; ++kk) qf[kk] = *(const f16x8*)(qp + kk * 32);
    }

    f32x4 o[8] = {};
    float m[4], lsum[4];
    #pragma unroll
    for (int r = 0; r < 4; ++r) { m[r] = -3e38f; lsum[r] = 0.f; }

    f16* Pw = (f16*)smem + w * 640;

    const int start = (w * npure) >> 3;
    const int end   = ((w + 1) * npure) >> 3;
    for (int tau = start; tau < end; ++tau) {
        const int t0 = tau << 5;

        f16x8 kf[2][4];
        #pragma unroll
        for (int tn = 0; tn < 2; ++tn) {
            const float* kp = Kb + (size_t)(t0 + tn * 16 + (l & 15)) * 128 + (l >> 4) * 8;
            #pragma unroll
            for (int kk = 0; kk < 4; ++kk) {
                float4 x = *(const float4*)(kp + kk * 32);
                float4 y = *(const float4*)(kp + kk * 32 + 4);
                kf[tn][kk] = cvt8(x, y);
            }
        }
        f32x4 sa[2] = {};
        #pragma unroll
        for (int tn = 0; tn < 2; ++tn)
            #pragma unroll
            for (int kk = 0; kk < 4; ++kk) sa[tn] = MFMA16(qf[kk], kf[tn][kk], sa[tn]);

        f16x8 vf[8];
        {
            const float* vp = Vb + (size_t)(t0 + (l >> 4) * 8) * 128 + (l & 15);
            #pragma unroll
            for (int dt = 0; dt < 8; ++dt)
                #pragma unroll
                for (int j = 0; j < 8; ++j) vf[dt][j] = (f16)vp[j * 128 + dt * 16];
        }

        float sc[2][4];
        #pragma unroll
        for (int tn = 0; tn < 2; ++tn)
            #pragma unroll
            for (int r = 0; r < 4; ++r) sc[tn][r] = sa[tn][r] * SCL;
        float vmax[4];
        #pragma unroll
        for (int r = 0; r < 4; ++r) vmax[r] = fmaxf(sc[0][r], sc[1][r]);
        #pragma unroll
        for (int d = 1; d < 16; d <<= 1)
            #pragma unroll
            for (int r = 0; r < 4; ++r) vmax[r] = fmaxf(vmax[r], __shfl_xor(vmax[r], d));
        float p[2][4], rs[4], fac[4];
        #pragma unroll
        for (int r = 0; r < 4; ++r) {
            const float mn = fmaxf(m[r], vmax[r]);
            fac[r] = exp2f(m[r] - mn);
            m[r] = mn;
            p[0][r] = exp2f(sc[0][r] - mn);
            p[1][r] = exp2f(sc[1][r] - mn);
            rs[r] = p[0][r] + p[1][r];
            lsum[r] *= fac[r];
        }
        #pragma unroll
        for (int d = 1; d < 16; d <<= 1)
            #pragma unroll
            for (int r = 0; r < 4; ++r) rs[r] += __shfl_xor(rs[r], d);
        #pragma unroll
        for (int r = 0; r < 4; ++r) lsum[r] += rs[r];
        #pragma unroll
        for (int dt = 0; dt < 8; ++dt)
            #pragma unroll
            for (int r = 0; r < 4; ++r) o[dt][r] *= fac[r];

        #pragma unroll
        for (int r = 0; r < 4; ++r) {
            const int s_ = (l >> 4) * 4 + r;
            Pw[s_ * 40 + (l & 15)]      = (f16)p[0][r];
            Pw[s_ * 40 + 16 + (l & 15)] = (f16)p[1][r];
        }
        asm volatile("s_waitcnt lgkmcnt(0)" ::: "memory");
        f16x8 pa = *(const f16x8*)(Pw + (l & 15) * 40 + (l >> 4) * 8);

        #pragma unroll
        for (int dt = 0; dt < 8; ++dt) o[dt] = MFMA16(pa, vf[dt], o[dt]);
    }

    // ---- boundary tiles (cache tail + 16 new rows): wave 7 only ----
    if (w == 7) {
        for (int t0 = npure << 5; t0 < pos + 16; t0 += 32) {
            f32x4 sa[2] = {};
            bool tnv[2];
            #pragma unroll
            for (int tn = 0; tn < 2; ++tn) {
                tnv[tn] = (t0 + tn * 16 < pos + 16);
                if (!tnv[tn]) continue;
                const int trow = t0 + tn * 16 + (l & 15);
                f16x8 kf[4];
                if (trow < pos) {
                    const float* kp = Kb + (size_t)trow * 128 + (l >> 4) * 8;
                    #pragma unroll
                    for (int kk = 0; kk < 4; ++kk) {
                        float4 x = *(const float4*)(kp + kk * 32);
                        float4 y = *(const float4*)(kp + kk * 32 + 4);
                        kf[kk] = cvt8(x, y);
                    }
                } else {
                    const int tt = trow - pos;
                    const int rr = tt < 15 ? tt : 15;
                    const f16* kp = Kw + (size_t)(b * 16 + rr) * HID + hh * 128 + (l >> 4) * 8;
                    #pragma unroll
                    for (int kk = 0; kk < 4; ++kk) kf[kk] = *(const f16x8*)(kp + kk * 32);
                }
                #pragma unroll
                for (int kk = 0; kk < 4; ++kk) sa[tn] = MFMA16(qf[kk], kf[kk], sa[tn]);
            }

            float sc[2][4];
            #pragma unroll
            for (int tn = 0; tn < 2; ++tn) {
                const int tg = t0 + tn * 16 + (l & 15);
                #pragma unroll
                for (int r = 0; r < 4; ++r) {
                    if (!tnv[tn]) { sc[tn][r] = -3e38f; continue; }
                    float v = sa[tn][r] * SCL;
                    if (tg >= pos) {
                        const int tt = tg - pos;
                        const int s_ = (l >> 4) * 4 + r;
                        if (tt > s_ || tt >= 16) v = -3e38f;
                    }
                    sc[tn][r] = v;
                }
            }

            float vmax[4];
            #pragma unroll
            for (int r = 0; r < 4; ++r) vmax[r] = fmaxf(sc[0][r], sc[1][r]);
            #pragma unroll
            for (int d = 1; d < 16; d <<= 1)
                #pragma unroll
                for (int r = 0; r < 4; ++r) vmax[r] = fmaxf(vmax[r], __shfl_xor(vmax[r], d));
            float p[2][4], rs[4], fac[4];
            #pragma unroll
            for (int r = 0; r < 4; ++r) {
                const float mn = fmaxf(m[r], vmax[r]);
                fac[r] = exp2f(m[r] - mn);
                m[r] = mn;
                p[0][r] = sc[0][r] < -1e29f ? 0.f : exp2f(sc[0][r] - mn);
                p[1][r] = sc[1][r] < -1e29f ? 0.f : exp2f(sc[1][r] - mn);
                rs[r] = p[0][r] + p[1][r];
                lsum[r] *= fac[r];
            }
            #pragma unroll
            for (int d = 1; d < 16; d <<= 1)
                #pragma unroll
                for (int r = 0; r < 4; ++r) rs[r] += __shfl_xor(rs[r], d);
            #pragma unroll
            for (int r = 0; r < 4; ++r) lsum[r] += rs[r];
            #pragma unroll
            for (int dt = 0; dt < 8; ++dt)
                #pragma unroll
                for (int r = 0; r < 4; ++r) o[dt][r] *= fac[r];

            #pragma unroll
            for (int r = 0; r < 4; ++r) {
                const int s_ = (l >> 4) * 4 + r;
                Pw[s_ * 40 + (l & 15)]      = (f16)p[0][r];
                Pw[s_ * 40 + 16 + (l & 15)] = (f16)p[1][r];
            }
            asm volatile("s_waitcnt lgkmcnt(0)" ::: "memory");
            f16x8 pa = *(const f16x8*)(Pw + (l & 15) * 40 + (l >> 4) * 8);

            const int tb = t0 + (l >> 4) * 8;
            #pragma unroll
            for (int dt = 0; dt < 8; ++dt) {
                f16x8 vf;
                #pragma unroll
                for (int j = 0; j < 8; ++j) {
                    const int t = tb + j;
                    if (t < pos) {
                        vf[j] = (f16)Vb[(size_t)t * 128 + dt * 16 + (l & 15)];
                    } else {
                        const int rr = (t - pos < 15) ? (t - pos) : 15;
                        vf[j] = Vw[(size_t)(b * 16 + rr) * HID + hh * 128 + dt * 16 + (l & 15)];
                    }
                }
                o[dt] = MFMA16(pa, vf, o[dt]);
            }
        }
    }

    // ---- merge 8 per-wave partials ----
    __syncthreads();
    float* Osh = (float*)smem;                 // [8][16][128]
    float* Msh = (float*)(smem + 65536);       // [8][16]
    float* Lsh = Msh + 128;
    #pragma unroll
    for (int dt = 0; dt < 8; ++dt)
        #pragma unroll
        for (int r = 0; r < 4; ++r)
            Osh[w * 2048 + ((l >> 4) * 4 + r) * 128 + dt * 16 + (l & 15)] = o[dt][r];
    if ((l & 15) == 0) {
        #pragma unroll
        for (int r = 0; r < 4; ++r) {
            Msh[w * 16 + (l >> 4) * 4 + r] = m[r];
            Lsh[w * 16 + (l >> 4) * 4 + r] = lsum[r];
        }
    }
    __syncthreads();
    {
        const int s_ = tid >> 5;           // 0..15
        const int d_ = (tid & 31) * 4;     // 0..124
        float M = -3e38f;
        #pragma unroll
        for (int ww = 0; ww < 8; ++ww) M = fmaxf(M, Msh[ww * 16 + s_]);
        float L = 0.f;
        f32x4 oa = {};
        #pragma unroll
        for (int ww = 0; ww < 8; ++ww) {
            const float e = exp2f(Msh[ww * 16 + s_] - M);
            L += e * Lsh[ww * 16 + s_];
            f32x4 v = *(const f32x4*)(Osh + ww * 2048 + s_ * 128 + d_);
            #pragma unroll
            for (int r = 0; r < 4; ++r) oa[r] += e * v[r];
        }
        const float inv = 1.f / L;
        f16x4 res = {(f16)(oa[0] * inv), (f16)(oa[1] * inv),
                     (f16)(oa[2] * inv), (f16)(oa[3] * inv)};
        *(f16x4*)(Ow + (size_t)(b * 16 + s_) * HID + hh * 128 + d_) = res;
    }
}

extern "C" void kernel_launch(void* const* d_in, const int* in_sizes, int n_in,
                              void* d_out, int out_size, void* d_ws, size_t ws_size,
                              hipStream_t stream) {
    const float* h  = (const float*)d_in[0];
    const float* Wq = (const float*)d_in[1];
    const float* Wk = (const float*)d_in[2];
    const float* Wv = (const float*)d_in[3];
    const float* Wo = (const float*)d_in[4];
    const float* Kc = (const float*)d_in[5];
    const float* Vc = (const float*)d_in[6];
    const int* pos  = (const int*)d_in[7];
    float* out = (float*)d_out;

    f16* hws = (f16*)d_ws;            // 128*4096 f16 = 1 MB
    f16* Qw  = hws + ROWS * HID;
    f16* Kw  = Qw + ROWS * HID;
    f16* Vw  = Kw + ROWS * HID;
    f16* Ow  = Vw + ROWS * HID;

    k_cvt<<<256, 256, 0, stream>>>(h, hws);
    k_proj<<<768, 256, 0, stream>>>(hws, Wq, Wk, Wv, Qw, Kw, Vw);
    k_attn<<<256, 512, 0, stream>>>(Qw, Kw, Vw, Kc, Vc, pos, Ow);
    k_oproj<<<256, 256, 0, stream>>>(Ow, Wo, out);
}

// Round 8
// 221.137 us; speedup vs baseline: 5.3829x; 1.2245x over previous
//
#include <hip/hip_runtime.h>

typedef _Float16 f16;
typedef _Float16 f16x8 __attribute__((ext_vector_type(8)));
typedef _Float16 f16x4 __attribute__((ext_vector_type(4)));
typedef float f32x4 __attribute__((ext_vector_type(4)));

#define MFMA16(a, b, c) __builtin_amdgcn_mfma_f32_16x16x32_f16(a, b, c, 0, 0, 0)

#define HID 4096
#define ROWS 128          // B*S
#define PH (ROWS * HID)   // one partial matrix (elements)
#define SCL 0.12751743f   // (1/sqrt(128)) * log2(e)

__device__ __forceinline__ f16x8 cvt8(float4 x, float4 y) {
    f16x8 v = {(f16)x.x, (f16)x.y, (f16)x.z, (f16)x.w,
               (f16)y.x, (f16)y.y, (f16)y.z, (f16)y.w};
    return v;
}

// element-wise sum of two fp32 partials -> f16x8
__device__ __forceinline__ f16x8 cvt8s(float4 x0, float4 x1, float4 y0, float4 y1) {
    f16x8 v = {(f16)(x0.x + x1.x), (f16)(x0.y + x1.y),
               (f16)(x0.z + x1.z), (f16)(x0.w + x1.w),
               (f16)(y0.x + y1.x), (f16)(y0.y + y1.y),
               (f16)(y0.z + y1.z), (f16)(y0.w + y1.w)};
    return v;
}

// XOR swizzle for a tile with 128 f16 (256 B) row pitch
__device__ __forceinline__ int swz2(int row, int cb) {
    return row * 256 + (cb ^ ((row & 7) << 4));
}

// ---------------- kernel 0: h fp32 -> f16 ----------------
__global__ void k_cvt(const float* __restrict__ src, f16* __restrict__ dst) {
    const int i = blockIdx.x * blockDim.x + threadIdx.x;
    const float4* s4 = (const float4*)src + (size_t)i * 2;
    float4 x = s4[0], y = s4[1];
    *((f16x8*)dst + i) = cvt8(x, y);
}

// ---------------- kernel A: fused QKV projection, K-split x2 ----------------
// R2's proven cooperative-staging core; grid 1536 = mat(3) x ct(256) x half(2).
// Each block computes a K=2048 partial (fp32) -> consumers sum the two halves.
// 4 resident blocks/CU (LDS 36.8KB) vs 3 before: occupancy 29% -> ~50%.
__global__ __launch_bounds__(256) void k_proj(
        const f16* __restrict__ hb,
        const float* __restrict__ Wq, const float* __restrict__ Wk,
        const float* __restrict__ Wv,
        float* __restrict__ Qp, float* __restrict__ Kp, float* __restrict__ Vp) {
    const int half = blockIdx.x & 1;
    const int ct   = (blockIdx.x >> 1) & 255;
    const int mat  = blockIdx.x >> 9;
    const float* __restrict__ W = (mat == 0) ? Wq : (mat == 1) ? Wk : Wv;
    float* __restrict__ Pb = ((mat == 0) ? Qp : (mat == 1) ? Kp : Vp) + (size_t)half * PH;
    const int c0  = ct * 16;
    const int k00 = half * 2048;

    __shared__ __align__(16) f16 sA[128 * 128];
    __shared__ __align__(16) f16 sB[16 * 128];

    const int tid = threadIdx.x;
    const int w = tid >> 6, l = tid & 63;
    const int rw = w * 32;
    const int ar = tid >> 4;
    const int ac = (tid & 15) * 8;

    f32x4 acc0 = {}, acc1 = {};

    float4 wx, wy;
    f16x8 hreg[8];
    {
        const float* wp = W + (size_t)(c0 + ar) * HID + k00 + ac;
        wx = *(const float4*)wp; wy = *(const float4*)(wp + 4);
        #pragma unroll
        for (int c = 0; c < 8; ++c)
            hreg[c] = *(const f16x8*)(hb + (size_t)(c * 16 + ar) * HID + k00 + ac);
    }

    for (int ks = 0; ks < 16; ++ks) {
        #pragma unroll
        for (int c = 0; c < 8; ++c)
            *(f16x8*)((char*)sA + swz2(c * 16 + ar, ac * 2)) = hreg[c];
        *(f16x8*)((char*)sB + swz2(ar, ac * 2)) = cvt8(wx, wy);
        __syncthreads();
        if (ks < 15) {
            const int k0 = k00 + (ks + 1) * 128;
            const float* wp = W + (size_t)(c0 + ar) * HID + k0 + ac;
            wx = *(const float4*)wp; wy = *(const float4*)(wp + 4);
            #pragma unroll
            for (int c = 0; c < 8; ++c)
                hreg[c] = *(const f16x8*)(hb + (size_t)(c * 16 + ar) * HID + k0 + ac);
        }
        #pragma unroll
        for (int kk = 0; kk < 4; ++kk) {
            const int cb = kk * 64 + (l >> 4) * 16;
            f16x8 a0 = *(const f16x8*)((char*)sA + swz2(rw + (l & 15), cb));
            f16x8 a1 = *(const f16x8*)((char*)sA + swz2(rw + 16 + (l & 15), cb));
            f16x8 b0 = *(const f16x8*)((char*)sB + swz2((l & 15), cb));
            acc0 = MFMA16(a0, b0, acc0);
            acc1 = MFMA16(a1, b0, acc1);
        }
        __syncthreads();
    }
    #pragma unroll
    for (int r = 0; r < 4; ++r) {
        const int col = c0 + (l & 15);
        Pb[(size_t)(rw + (l >> 4) * 4 + r) * HID + col]      = acc0[r];
        Pb[(size_t)(rw + 16 + (l >> 4) * 4 + r) * HID + col] = acc1[r];
    }
}

// ---------------- kernel B: flash attention, 1 block per (b,h), 8 waves ----------------
// R2 structure (measured at KV HBM floor in R5); Q and boundary K/V now read
// as the sum of the two fp32 K-split partials (prologue/boundary only).
__global__ __launch_bounds__(512) void k_attn(
        const float* __restrict__ Qp, const float* __restrict__ Kp,
        const float* __restrict__ Vp,
        const float* __restrict__ Kc, const float* __restrict__ Vc,
        const int* __restrict__ posp, f16* __restrict__ Ow) {

    __shared__ __align__(16) char smem[65536 + 1024];

    const int bh = blockIdx.x;
    const int b = bh >> 5, hh = bh & 31;
    const int tid = threadIdx.x, w = tid >> 6, l = tid & 63;
    const int pos = *posp;
    const int npure = pos >> 5;

    const float* Kb = Kc + (size_t)bh * (4096 * 128);
    const float* Vb = Vc + (size_t)bh * (4096 * 128);

    // Q fragments: sum of two partials -> f16
    f16x8 qf[4];
    {
        const float* q0 = Qp + (size_t)(b * 16 + (l & 15)) * HID + hh * 128 + (l >> 4) * 8;
        const float* q1 = q0 + PH;
        #pragma unroll
        for (int kk = 0; kk < 4; ++kk)
            qf[kk] = cvt8s(*(const float4*)(q0 + kk * 32),     *(const float4*)(q1 + kk * 32),
                           *(const float4*)(q0 + kk * 32 + 4), *(const float4*)(q1 + kk * 32 + 4));
    }

    f32x4 o[8] = {};
    float m[4], lsum[4];
    #pragma unroll
    for (int r = 0; r < 4; ++r) { m[r] = -3e38f; lsum[r] = 0.f; }

    f16* Pw = (f16*)smem + w * 640;

    const int start = (w * npure) >> 3;
    const int end   = ((w + 1) * npure) >> 3;
    for (int tau = start; tau < end; ++tau) {
        const int t0 = tau << 5;

        f16x8 kf[2][4];
        #pragma unroll
        for (int tn = 0; tn < 2; ++tn) {
            const float* kp = Kb + (size_t)(t0 + tn * 16 + (l & 15)) * 128 + (l >> 4) * 8;
            #pragma unroll
            for (int kk = 0; kk < 4; ++kk) {
                float4 x = *(const float4*)(kp + kk * 32);
                float4 y = *(const float4*)(kp + kk * 32 + 4);
                kf[tn][kk] = cvt8(x, y);
            }
        }
        f32x4 sa[2] = {};
        #pragma unroll
        for (int tn = 0; tn < 2; ++tn)
            #pragma unroll
            for (int kk = 0; kk < 4; ++kk) sa[tn] = MFMA16(qf[kk], kf[tn][kk], sa[tn]);

        f16x8 vf[8];
        {
            const float* vp = Vb + (size_t)(t0 + (l >> 4) * 8) * 128 + (l & 15);
            #pragma unroll
            for (int dt = 0; dt < 8; ++dt)
                #pragma unroll
                for (int j = 0; j < 8; ++j) vf[dt][j] = (f16)vp[j * 128 + dt * 16];
        }

        float sc[2][4];
        #pragma unroll
        for (int tn = 0; tn < 2; ++tn)
            #pragma unroll
            for (int r = 0; r < 4; ++r) sc[tn][r] = sa[tn][r] * SCL;
        float vmax[4];
        #pragma unroll
        for (int r = 0; r < 4; ++r) vmax[r] = fmaxf(sc[0][r], sc[1][r]);
        #pragma unroll
        for (int d = 1; d < 16; d <<= 1)
            #pragma unroll
            for (int r = 0; r < 4; ++r) vmax[r] = fmaxf(vmax[r], __shfl_xor(vmax[r], d));
        float p[2][4], rs[4], fac[4];
        #pragma unroll
        for (int r = 0; r < 4; ++r) {
            const float mn = fmaxf(m[r], vmax[r]);
            fac[r] = exp2f(m[r] - mn);
            m[r] = mn;
            p[0][r] = exp2f(sc[0][r] - mn);
            p[1][r] = exp2f(sc[1][r] - mn);
            rs[r] = p[0][r] + p[1][r];
            lsum[r] *= fac[r];
        }
        #pragma unroll
        for (int d = 1; d < 16; d <<= 1)
            #pragma unroll
            for (int r = 0; r < 4; ++r) rs[r] += __shfl_xor(rs[r], d);
        #pragma unroll
        for (int r = 0; r < 4; ++r) lsum[r] += rs[r];
        #pragma unroll
        for (int dt = 0; dt < 8; ++dt)
            #pragma unroll
            for (int r = 0; r < 4; ++r) o[dt][r] *= fac[r];

        #pragma unroll
        for (int r = 0; r < 4; ++r) {
            const int s_ = (l >> 4) * 4 + r;
            Pw[s_ * 40 + (l & 15)]      = (f16)p[0][r];
            Pw[s_ * 40 + 16 + (l & 15)] = (f16)p[1][r];
        }
        asm volatile("s_waitcnt lgkmcnt(0)" ::: "memory");
        f16x8 pa = *(const f16x8*)(Pw + (l & 15) * 40 + (l >> 4) * 8);

        #pragma unroll
        for (int dt = 0; dt < 8; ++dt) o[dt] = MFMA16(pa, vf[dt], o[dt]);
    }

    // ---- boundary tiles (cache tail + 16 new rows): wave 7 only ----
    if (w == 7) {
        for (int t0 = npure << 5; t0 < pos + 16; t0 += 32) {
            f32x4 sa[2] = {};
            bool tnv[2];
            #pragma unroll
            for (int tn = 0; tn < 2; ++tn) {
                tnv[tn] = (t0 + tn * 16 < pos + 16);
                if (!tnv[tn]) continue;
                const int trow = t0 + tn * 16 + (l & 15);
                f16x8 kf[4];
                if (trow < pos) {
                    const float* kp = Kb + (size_t)trow * 128 + (l >> 4) * 8;
                    #pragma unroll
                    for (int kk = 0; kk < 4; ++kk) {
                        float4 x = *(const float4*)(kp + kk * 32);
                        float4 y = *(const float4*)(kp + kk * 32 + 4);
                        kf[kk] = cvt8(x, y);
                    }
                } else {
                    const int tt = trow - pos;
                    const int rr = tt < 15 ? tt : 15;
                    const float* k0 = Kp + (size_t)(b * 16 + rr) * HID + hh * 128 + (l >> 4) * 8;
                    const float* k1 = k0 + PH;
                    #pragma unroll
                    for (int kk = 0; kk < 4; ++kk)
                        kf[kk] = cvt8s(*(const float4*)(k0 + kk * 32),     *(const float4*)(k1 + kk * 32),
                                       *(const float4*)(k0 + kk * 32 + 4), *(const float4*)(k1 + kk * 32 + 4));
                }
                #pragma unroll
                for (int kk = 0; kk < 4; ++kk) sa[tn] = MFMA16(qf[kk], kf[kk], sa[tn]);
            }

            float sc[2][4];
            #pragma unroll
            for (int tn = 0; tn < 2; ++tn) {
                const int tg = t0 + tn * 16 + (l & 15);
                #pragma unroll
                for (int r = 0; r < 4; ++r) {
                    if (!tnv[tn]) { sc[tn][r] = -3e38f; continue; }
                    float v = sa[tn][r] * SCL;
                    if (tg >= pos) {
                        const int tt = tg - pos;
                        const int s_ = (l >> 4) * 4 + r;
                        if (tt > s_ || tt >= 16) v = -3e38f;
                    }
                    sc[tn][r] = v;
                }
            }

            float vmax[4];
            #pragma unroll
            for (int r = 0; r < 4; ++r) vmax[r] = fmaxf(sc[0][r], sc[1][r]);
            #pragma unroll
            for (int d = 1; d < 16; d <<= 1)
                #pragma unroll
                for (int r = 0; r < 4; ++r) vmax[r] = fmaxf(vmax[r], __shfl_xor(vmax[r], d));
            float p[2][4], rs[4], fac[4];
            #pragma unroll
            for (int r = 0; r < 4; ++r) {
                const float mn = fmaxf(m[r], vmax[r]);
                fac[r] = exp2f(m[r] - mn);
                m[r] = mn;
                p[0][r] = sc[0][r] < -1e29f ? 0.f : exp2f(sc[0][r] - mn);
                p[1][r] = sc[1][r] < -1e29f ? 0.f : exp2f(sc[1][r] - mn);
                rs[r] = p[0][r] + p[1][r];
                lsum[r] *= fac[r];
            }
            #pragma unroll
            for (int d = 1; d < 16; d <<= 1)
                #pragma unroll
                for (int r = 0; r < 4; ++r) rs[r] += __shfl_xor(rs[r], d);
            #pragma unroll
            for (int r = 0; r < 4; ++r) lsum[r] += rs[r];
            #pragma unroll
            for (int dt = 0; dt < 8; ++dt)
                #pragma unroll
                for (int r = 0; r < 4; ++r) o[dt][r] *= fac[r];

            #pragma unroll
            for (int r = 0; r < 4; ++r) {
                const int s_ = (l >> 4) * 4 + r;
                Pw[s_ * 40 + (l & 15)]      = (f16)p[0][r];
                Pw[s_ * 40 + 16 + (l & 15)] = (f16)p[1][r];
            }
            asm volatile("s_waitcnt lgkmcnt(0)" ::: "memory");
            f16x8 pa = *(const f16x8*)(Pw + (l & 15) * 40 + (l >> 4) * 8);

            const int tb = t0 + (l >> 4) * 8;
            #pragma unroll
            for (int dt = 0; dt < 8; ++dt) {
                f16x8 vf;
                #pragma unroll
                for (int j = 0; j < 8; ++j) {
                    const int t = tb + j;
                    if (t < pos) {
                        vf[j] = (f16)Vb[(size_t)t * 128 + dt * 16 + (l & 15)];
                    } else {
                        const int rr = (t - pos < 15) ? (t - pos) : 15;
                        const size_t off = (size_t)(b * 16 + rr) * HID + hh * 128 + dt * 16 + (l & 15);
                        vf[j] = (f16)(Vp[off] + Vp[off + PH]);
                    }
                }
                o[dt] = MFMA16(pa, vf, o[dt]);
            }
        }
    }

    // ---- merge 8 per-wave partials ----
    __syncthreads();
    float* Osh = (float*)smem;                 // [8][16][128]
    float* Msh = (float*)(smem + 65536);       // [8][16]
    float* Lsh = Msh + 128;
    #pragma unroll
    for (int dt = 0; dt < 8; ++dt)
        #pragma unroll
        for (int r = 0; r < 4; ++r)
            Osh[w * 2048 + ((l >> 4) * 4 + r) * 128 + dt * 16 + (l & 15)] = o[dt][r];
    if ((l & 15) == 0) {
        #pragma unroll
        for (int r = 0; r < 4; ++r) {
            Msh[w * 16 + (l >> 4) * 4 + r] = m[r];
            Lsh[w * 16 + (l >> 4) * 4 + r] = lsum[r];
        }
    }
    __syncthreads();
    {
        const int s_ = tid >> 5;           // 0..15
        const int d_ = (tid & 31) * 4;     // 0..124
        float M = -3e38f;
        #pragma unroll
        for (int ww = 0; ww < 8; ++ww) M = fmaxf(M, Msh[ww * 16 + s_]);
        float L = 0.f;
        f32x4 oa = {};
        #pragma unroll
        for (int ww = 0; ww < 8; ++ww) {
            const float e = exp2f(Msh[ww * 16 + s_] - M);
            L += e * Lsh[ww * 16 + s_];
            f32x4 v = *(const f32x4*)(Osh + ww * 2048 + s_ * 128 + d_);
            #pragma unroll
            for (int r = 0; r < 4; ++r) oa[r] += e * v[r];
        }
        const float inv = 1.f / L;
        f16x4 res = {(f16)(oa[0] * inv), (f16)(oa[1] * inv),
                     (f16)(oa[2] * inv), (f16)(oa[3] * inv)};
        *(f16x4*)(Ow + (size_t)(b * 16 + s_) * HID + hh * 128 + d_) = res;
    }
}

// ---------------- kernel C: output projection (R2, unchanged) ----------------
__global__ __launch_bounds__(256) void k_oproj(
        const f16* __restrict__ Oa, const float* __restrict__ Wo,
        float* __restrict__ out) {
    const int c0 = blockIdx.x * 16;

    __shared__ __align__(16) f16 sA[128 * 128];
    __shared__ __align__(16) f16 sB[16 * 128];

    const int tid = threadIdx.x;
    const int w = tid >> 6, l = tid & 63;
    const int rw = w * 32;
    const int ar = tid >> 4;
    const int ac = (tid & 15) * 8;

    f32x4 acc0 = {}, acc1 = {};

    float4 wx, wy;
    f16x8 hreg[8];
    {
        const float* wp = Wo + (size_t)(c0 + ar) * HID + ac;
        wx = *(const float4*)wp; wy = *(const float4*)(wp + 4);
        #pragma unroll
        for (int c = 0; c < 8; ++c)
            hreg[c] = *(const f16x8*)(Oa + (size_t)(c * 16 + ar) * HID + ac);
    }

    for (int ks = 0; ks < 32; ++ks) {
        #pragma unroll
        for (int c = 0; c < 8; ++c)
            *(f16x8*)((char*)sA + swz2(c * 16 + ar, ac * 2)) = hreg[c];
        *(f16x8*)((char*)sB + swz2(ar, ac * 2)) = cvt8(wx, wy);
        __syncthreads();
        if (ks < 31) {
            const int k0 = (ks + 1) * 128;
            const float* wp = Wo + (size_t)(c0 + ar) * HID + k0 + ac;
            wx = *(const float4*)wp; wy = *(const float4*)(wp + 4);
            #pragma unroll
            for (int c = 0; c < 8; ++c)
                hreg[c] = *(const f16x8*)(Oa + (size_t)(c * 16 + ar) * HID + k0 + ac);
        }
        #pragma unroll
        for (int kk = 0; kk < 4; ++kk) {
            const int cb = kk * 64 + (l >> 4) * 16;
            f16x8 a0 = *(const f16x8*)((char*)sA + swz2(rw + (l & 15), cb));
            f16x8 a1 = *(const f16x8*)((char*)sA + swz2(rw + 16 + (l & 15), cb));
            f16x8 b0 = *(const f16x8*)((char*)sB + swz2((l & 15), cb));
            acc0 = MFMA16(a0, b0, acc0);
            acc1 = MFMA16(a1, b0, acc1);
        }
        __syncthreads();
    }
    #pragma unroll
    for (int r = 0; r < 4; ++r) {
        const int col = c0 + (l & 15);
        out[(size_t)(rw + (l >> 4) * 4 + r) * HID + col]      = acc0[r];
        out[(size_t)(rw + 16 + (l >> 4) * 4 + r) * HID + col] = acc1[r];
    }
}

extern "C" void kernel_launch(void* const* d_in, const int* in_sizes, int n_in,
                              void* d_out, int out_size, void* d_ws, size_t ws_size,
                              hipStream_t stream) {
    const float* h  = (const float*)d_in[0];
    const float* Wq = (const float*)d_in[1];
    const float* Wk = (const float*)d_in[2];
    const float* Wv = (const float*)d_in[3];
    const float* Wo = (const float*)d_in[4];
    const float* Kc = (const float*)d_in[5];
    const float* Vc = (const float*)d_in[6];
    const int* pos  = (const int*)d_in[7];
    float* out = (float*)d_out;

    f16* hws  = (f16*)d_ws;                    // 128x4096 f16 = 1 MB
    float* Qp = (float*)(hws + ROWS * HID);    // 2 partials x 2 MB
    float* Kp = Qp + 2 * PH;
    float* Vp = Kp + 2 * PH;
    f16* Ow   = (f16*)(Vp + 2 * PH);           // 1 MB

    k_cvt<<<256, 256, 0, stream>>>(h, hws);
    k_proj<<<1536, 256, 0, stream>>>(hws, Wq, Wk, Wv, Qp, Kp, Vp);
    k_attn<<<256, 512, 0, stream>>>(Qp, Kp, Vp, Kc, Vc, pos, Ow);
    k_oproj<<<256, 256, 0, stream>>>(Ow, Wo, out);
}

// Round 9
// 208.646 us; speedup vs baseline: 5.7051x; 1.0599x over previous
//
#include <hip/hip_runtime.h>

typedef _Float16 f16;
typedef _Float16 f16x8 __attribute__((ext_vector_type(8)));
typedef _Float16 f16x4 __attribute__((ext_vector_type(4)));
typedef float f32x4 __attribute__((ext_vector_type(4)));

#define MFMA16(a, b, c) __builtin_amdgcn_mfma_f32_16x16x32_f16(a, b, c, 0, 0, 0)

#define HID 4096
#define ROWS 128          // B*S
#define SCL 0.12751743f   // (1/sqrt(128)) * log2(e)

__device__ __forceinline__ f16x8 cvt8(float4 x, float4 y) {
    f16x8 v = {(f16)x.x, (f16)x.y, (f16)x.z, (f16)x.w,
               (f16)y.x, (f16)y.y, (f16)y.z, (f16)y.w};
    return v;
}

// XOR swizzle for a tile with 128 f16 (256 B) row pitch
__device__ __forceinline__ int swz2(int row, int cb) {
    return row * 256 + (cb ^ ((row & 7) << 4));
}

// ---------------- kernel 0: h fp32 -> f16 ----------------
__global__ void k_cvt(const float* __restrict__ src, f16* __restrict__ dst) {
    const int i = blockIdx.x * blockDim.x + threadIdx.x;
    const float4* s4 = (const float4*)src + (size_t)i * 2;
    float4 x = s4[0], y = s4[1];
    *((f16x8*)dst + i) = cvt8(x, y);
}

// ======================================================================
// Projection GEMM core: R2's tile/staging/MFMA, but RAW-barrier pipeline.
// __syncthreads (vmcnt(0) drain) replaced by s_barrier + counted waits:
//  - sB (W tile) double-buffered: ds_write sB[next] from regs loaded last
//    iter; the W(k+2) loads issued this iter stay IN FLIGHT across both
//    barriers (compiler emits counted vmcnt for register dataflow).
//  - sA single-buffered: h(k+1) loads issued this iter, written after
//    barrier#1 (all sA reads done), visible after lgkmcnt(0)+barrier#2.
// LDS 40 KB -> 3 blocks/CU. W in-flight window: ~1 full iteration.
// ======================================================================
__device__ __forceinline__ void gemm_core(
        const f16* __restrict__ Ab, const float* __restrict__ W,
        int c0, int tid, f16* __restrict__ sA, f16* __restrict__ sB,
        f32x4& acc0, f32x4& acc1) {
    const int w = tid >> 6, l = tid & 63;
    const int rw = w * 32;
    const int ar = tid >> 4;          // 0..15
    const int ac = (tid & 15) * 8;    // element col within 128-chunk

    const float* wrow = W + (size_t)(c0 + ar) * HID + ac;
    const f16*   arow = Ab + (size_t)ar * HID + ac;

    float4 wx, wy, wnx = {}, wny = {};

    // prologue: W(0), h(0) -> LDS; preload W(1) into regs
    {
        float4 w0x = *(const float4*)wrow;
        float4 w0y = *(const float4*)(wrow + 4);
        *(f16x8*)((char*)sB + swz2(ar, ac * 2)) = cvt8(w0x, w0y);
        #pragma unroll
        for (int c = 0; c < 8; ++c) {
            f16x8 hv = *(const f16x8*)(arow + (size_t)c * 16 * HID);
            *(f16x8*)((char*)sA + swz2(c * 16 + ar, ac * 2)) = hv;
        }
        wx = *(const float4*)(wrow + 128);
        wy = *(const float4*)(wrow + 128 + 4);
    }
    asm volatile("s_waitcnt lgkmcnt(0)" ::: "memory");
    __builtin_amdgcn_sched_barrier(0);
    __builtin_amdgcn_s_barrier();

    for (int ks = 0; ks < 32; ++ks) {
        const int buf = ks & 1;
        f16x8 Hn[8];
        if (ks < 31) {
            const int kh = (ks + 1) * 128;
            // issue h(k+1) loads (L2-hot, land before barrier#1 write)
            #pragma unroll
            for (int c = 0; c < 8; ++c)
                Hn[c] = *(const f16x8*)(arow + (size_t)c * 16 * HID + kh);
            // issue W(k+2) loads (HBM, in flight ~1 full iteration)
            if (ks < 30) {
                const float* wp = wrow + (ks + 2) * 128;
                wnx = *(const float4*)wp; wny = *(const float4*)(wp + 4);
            }
            // write next W tile from regs loaded LAST iter (counted vmcnt)
            *(f16x8*)((char*)sB + (buf ^ 1) * 4096 + swz2(ar, ac * 2)) = cvt8(wx, wy);
        }
        // MFMA on current buffers
        #pragma unroll
        for (int kk = 0; kk < 4; ++kk) {
            const int cb = kk * 64 + (l >> 4) * 16;
            f16x8 a0 = *(const f16x8*)((char*)sA + swz2(rw + (l & 15), cb));
            f16x8 a1 = *(const f16x8*)((char*)sA + swz2(rw + 16 + (l & 15), cb));
            f16x8 b0 = *(const f16x8*)((char*)sB + buf * 4096 + swz2((l & 15), cb));
            acc0 = MFMA16(a0, b0, acc0);
            acc1 = MFMA16(a1, b0, acc1);
        }
        if (ks < 31) {
            __builtin_amdgcn_sched_barrier(0);
            __builtin_amdgcn_s_barrier();           // #1: all sA reads done
            #pragma unroll
            for (int c = 0; c < 8; ++c)
                *(f16x8*)((char*)sA + swz2(c * 16 + ar, ac * 2)) = Hn[c];
            wx = wnx; wy = wny;
            asm volatile("s_waitcnt lgkmcnt(0)" ::: "memory");
            __builtin_amdgcn_sched_barrier(0);
            __builtin_amdgcn_s_barrier();           // #2: LDS writes visible
        }
    }
}

// ---------------- kernel A: fused QKV projection ----------------
__global__ __launch_bounds__(256) void k_proj(
        const f16* __restrict__ hb,
        const float* __restrict__ Wq, const float* __restrict__ Wk,
        const float* __restrict__ Wv,
        f16* __restrict__ Qw, f16* __restrict__ Kw, f16* __restrict__ Vw) {
    const int mat = blockIdx.x >> 8;
    const int ct  = blockIdx.x & 255;
    const float* __restrict__ W = (mat == 0) ? Wq : (mat == 1) ? Wk : Wv;
    f16* __restrict__ Ob = (mat == 0) ? Qw : (mat == 1) ? Kw : Vw;
    const int c0 = ct * 16;

    __shared__ __align__(16) f16 sA[128 * 128];   // 32 KB
    __shared__ __align__(16) f16 sB[2 * 16 * 128]; // 8 KB double-buffered

    const int tid = threadIdx.x;
    const int w = tid >> 6, l = tid & 63;

    f32x4 acc0 = {}, acc1 = {};
    gemm_core(hb, W, c0, tid, sA, sB, acc0, acc1);

    #pragma unroll
    for (int r = 0; r < 4; ++r) {
        const int row = w * 32 + (l >> 4) * 4 + r;
        const int col = c0 + (l & 15);
        Ob[(size_t)row * HID + col]        = (f16)acc0[r];
        Ob[(size_t)(row + 16) * HID + col] = (f16)acc1[r];
    }
}

// ---------------- kernel C: output projection (same core, fp32 out) ----------------
__global__ __launch_bounds__(256) void k_oproj(
        const f16* __restrict__ Oa, const float* __restrict__ Wo,
        float* __restrict__ out) {
    const int c0 = blockIdx.x * 16;

    __shared__ __align__(16) f16 sA[128 * 128];
    __shared__ __align__(16) f16 sB[2 * 16 * 128];

    const int tid = threadIdx.x;
    const int w = tid >> 6, l = tid & 63;

    f32x4 acc0 = {}, acc1 = {};
    gemm_core(Oa, Wo, c0, tid, sA, sB, acc0, acc1);

    #pragma unroll
    for (int r = 0; r < 4; ++r) {
        const int row = w * 32 + (l >> 4) * 4 + r;
        const int col = c0 + (l & 15);
        out[(size_t)row * HID + col]        = acc0[r];
        out[(size_t)(row + 16) * HID + col] = acc1[r];
    }
}

// ---------------- kernel B: flash attention, 1 block per (b,h), 8 waves ----------------
// (byte-identical to R2 — measured at the 86us KV HBM floor in R5)
__global__ __launch_bounds__(512) void k_attn(
        const f16* __restrict__ Qw, const f16* __restrict__ Kw,
        const f16* __restrict__ Vw,
        const float* __restrict__ Kc, const float* __restrict__ Vc,
        const int* __restrict__ posp, f16* __restrict__ Ow) {

    __shared__ __align__(16) char smem[65536 + 1024];

    const int bh = blockIdx.x;
    const int b = bh >> 5, hh = bh & 31;
    const int tid = threadIdx.x, w = tid >> 6, l = tid & 63;
    const int pos = *posp;
    const int npure = pos >> 5;

    const float* Kb = Kc + (size_t)bh * (4096 * 128);
    const float* Vb = Vc + (size_t)bh * (4096 * 128);

    f16x8 qf[4];
    {
        const f16* qp = Qw + (size_t)(b * 16 + (l & 15)) * HID + hh * 128 + (l >> 4) * 8;
        #pragma unroll
        for (int kk = 0; kk < 4; ++kk) qf[kk] = *(const f16x8*)(qp + kk * 32);
    }

    f32x4 o[8] = {};
    float m[4], lsum[4];
    #pragma unroll
    for (int r = 0; r < 4; ++r) { m[r] = -3e38f; lsum[r] = 0.f; }

    f16* Pw = (f16*)smem + w * 640;

    const int start = (w * npure) >> 3;
    const int end   = ((w + 1) * npure) >> 3;
    for (int tau = start; tau < end; ++tau) {
        const int t0 = tau << 5;

        f16x8 kf[2][4];
        #pragma unroll
        for (int tn = 0; tn < 2; ++tn) {
            const float* kp = Kb + (size_t)(t0 + tn * 16 + (l & 15)) * 128 + (l >> 4) * 8;
            #pragma unroll
            for (int kk = 0; kk < 4; ++kk) {
                float4 x = *(const float4*)(kp + kk * 32);
                float4 y = *(const float4*)(kp + kk * 32 + 4);
                kf[tn][kk] = cvt8(x, y);
            }
        }
        f32x4 sa[2] = {};
        #pragma unroll
        for (int tn = 0; tn < 2; ++tn)
            #pragma unroll
            for (int kk = 0; kk < 4; ++kk) sa[tn] = MFMA16(qf[kk], kf[tn][kk], sa[tn]);

        f16x8 vf[8];
        {
            const float* vp = Vb + (size_t)(t0 + (l >> 4) * 8) * 128 + (l & 15);
            #pragma unroll
            for (int dt = 0; dt < 8; ++dt)
                #pragma unroll
                for (int j = 0; j < 8; ++j) vf[dt][j] = (f16)vp[j * 128 + dt * 16];
        }

        float sc[2][4];
        #pragma unroll
        for (int tn = 0; tn < 2; ++tn)
            #pragma unroll
            for (int r = 0; r < 4; ++r) sc[tn][r] = sa[tn][r] * SCL;
        float vmax[4];
        #pragma unroll
        for (int r = 0; r < 4; ++r) vmax[r] = fmaxf(sc[0][r], sc[1][r]);
        #pragma unroll
        for (int d = 1; d < 16; d <<= 1)
            #pragma unroll
            for (int r = 0; r < 4; ++r) vmax[r] = fmaxf(vmax[r], __shfl_xor(vmax[r], d));
        float p[2][4], rs[4], fac[4];
        #pragma unroll
        for (int r = 0; r < 4; ++r) {
            const float mn = fmaxf(m[r], vmax[r]);
            fac[r] = exp2f(m[r] - mn);
            m[r] = mn;
            p[0][r] = exp2f(sc[0][r] - mn);
            p[1][r] = exp2f(sc[1][r] - mn);
            rs[r] = p[0][r] + p[1][r];
            lsum[r] *= fac[r];
        }
        #pragma unroll
        for (int d = 1; d < 16; d <<= 1)
            #pragma unroll
            for (int r = 0; r < 4; ++r) rs[r] += __shfl_xor(rs[r], d);
        #pragma unroll
        for (int r = 0; r < 4; ++r) lsum[r] += rs[r];
        #pragma unroll
        for (int dt = 0; dt < 8; ++dt)
            #pragma unroll
            for (int r = 0; r < 4; ++r) o[dt][r] *= fac[r];

        #pragma unroll
        for (int r = 0; r < 4; ++r) {
            const int s_ = (l >> 4) * 4 + r;
            Pw[s_ * 40 + (l & 15)]      = (f16)p[0][r];
            Pw[s_ * 40 + 16 + (l & 15)] = (f16)p[1][r];
        }
        asm volatile("s_waitcnt lgkmcnt(0)" ::: "memory");
        f16x8 pa = *(const f16x8*)(Pw + (l & 15) * 40 + (l >> 4) * 8);

        #pragma unroll
        for (int dt = 0; dt < 8; ++dt) o[dt] = MFMA16(pa, vf[dt], o[dt]);
    }

    // ---- boundary tiles (cache tail + 16 new rows): wave 7 only ----
    if (w == 7) {
        for (int t0 = npure << 5; t0 < pos + 16; t0 += 32) {
            f32x4 sa[2] = {};
            bool tnv[2];
            #pragma unroll
            for (int tn = 0; tn < 2; ++tn) {
                tnv[tn] = (t0 + tn * 16 < pos + 16);
                if (!tnv[tn]) continue;
                const int trow = t0 + tn * 16 + (l & 15);
                f16x8 kf[4];
                if (trow < pos) {
                    const float* kp = Kb + (size_t)trow * 128 + (l >> 4) * 8;
                    #pragma unroll
                    for (int kk = 0; kk < 4; ++kk) {
                        float4 x = *(const float4*)(kp + kk * 32);
                        float4 y = *(const float4*)(kp + kk * 32 + 4);
                        kf[kk] = cvt8(x, y);
                    }
                } else {
                    const int tt = trow - pos;
                    const int rr = tt < 15 ? tt : 15;
                    const f16* kp = Kw + (size_t)(b * 16 + rr) * HID + hh * 128 + (l >> 4) * 8;
                    #pragma unroll
                    for (int kk = 0; kk < 4; ++kk) kf[kk] = *(const f16x8*)(kp + kk * 32);
                }
                #pragma unroll
                for (int kk = 0; kk < 4; ++kk) sa[tn] = MFMA16(qf[kk], kf[kk], sa[tn]);
            }

            float sc[2][4];
            #pragma unroll
            for (int tn = 0; tn < 2; ++tn) {
                const int tg = t0 + tn * 16 + (l & 15);
                #pragma unroll
                for (int r = 0; r < 4; ++r) {
                    if (!tnv[tn]) { sc[tn][r] = -3e38f; continue; }
                    float v = sa[tn][r] * SCL;
                    if (tg >= pos) {
                        const int tt = tg - pos;
                        const int s_ = (l >> 4) * 4 + r;
                        if (tt > s_ || tt >= 16) v = -3e38f;
                    }
                    sc[tn][r] = v;
                }
            }

            float vmax[4];
            #pragma unroll
            for (int r = 0; r < 4; ++r) vmax[r] = fmaxf(sc[0][r], sc[1][r]);
            #pragma unroll
            for (int d = 1; d < 16; d <<= 1)
                #pragma unroll
                for (int r = 0; r < 4; ++r) vmax[r] = fmaxf(vmax[r], __shfl_xor(vmax[r], d));
            float p[2][4], rs[4], fac[4];
            #pragma unroll
            for (int r = 0; r < 4; ++r) {
                const float mn = fmaxf(m[r], vmax[r]);
                fac[r] = exp2f(m[r] - mn);
                m[r] = mn;
                p[0][r] = sc[0][r] < -1e29f ? 0.f : exp2f(sc[0][r] - mn);
                p[1][r] = sc[1][r] < -1e29f ? 0.f : exp2f(sc[1][r] - mn);
                rs[r] = p[0][r] + p[1][r];
                lsum[r] *= fac[r];
            }
            #pragma unroll
            for (int d = 1; d < 16; d <<= 1)
                #pragma unroll
                for (int r = 0; r < 4; ++r) rs[r] += __shfl_xor(rs[r], d);
            #pragma unroll
            for (int r = 0; r < 4; ++r) lsum[r] += rs[r];
            #pragma unroll
            for (int dt = 0; dt < 8; ++dt)
                #pragma unroll
                for (int r = 0; r < 4; ++r) o[dt][r] *= fac[r];

            #pragma unroll
            for (int r = 0; r < 4; ++r) {
                const int s_ = (l >> 4) * 4 + r;
                Pw[s_ * 40 + (l & 15)]      = (f16)p[0][r];
                Pw[s_ * 40 + 16 + (l & 15)] = (f16)p[1][r];
            }
            asm volatile("s_waitcnt lgkmcnt(0)" ::: "memory");
            f16x8 pa = *(const f16x8*)(Pw + (l & 15) * 40 + (l >> 4) * 8);

            const int tb = t0 + (l >> 4) * 8;
            #pragma unroll
            for (int dt = 0; dt < 8; ++dt) {
                f16x8 vf;
                #pragma unroll
                for (int j = 0; j < 8; ++j) {
                    const int t = tb + j;
                    if (t < pos) {
                        vf[j] = (f16)Vb[(size_t)t * 128 + dt * 16 + (l & 15)];
                    } else {
                        const int rr = (t - pos < 15) ? (t - pos) : 15;
                        vf[j] = Vw[(size_t)(b * 16 + rr) * HID + hh * 128 + dt * 16 + (l & 15)];
                    }
                }
                o[dt] = MFMA16(pa, vf, o[dt]);
            }
        }
    }

    // ---- merge 8 per-wave partials ----
    __syncthreads();
    float* Osh = (float*)smem;                 // [8][16][128]
    float* Msh = (float*)(smem + 65536);       // [8][16]
    float* Lsh = Msh + 128;
    #pragma unroll
    for (int dt = 0; dt < 8; ++dt)
        #pragma unroll
        for (int r = 0; r < 4; ++r)
            Osh[w * 2048 + ((l >> 4) * 4 + r) * 128 + dt * 16 + (l & 15)] = o[dt][r];
    if ((l & 15) == 0) {
        #pragma unroll
        for (int r = 0; r < 4; ++r) {
            Msh[w * 16 + (l >> 4) * 4 + r] = m[r];
            Lsh[w * 16 + (l >> 4) * 4 + r] = lsum[r];
        }
    }
    __syncthreads();
    {
        const int s_ = tid >> 5;           // 0..15
        const int d_ = (tid & 31) * 4;     // 0..124
        float M = -3e38f;
        #pragma unroll
        for (int ww = 0; ww < 8; ++ww) M = fmaxf(M, Msh[ww * 16 + s_]);
        float L = 0.f;
        f32x4 oa = {};
        #pragma unroll
        for (int ww = 0; ww < 8; ++ww) {
            const float e = exp2f(Msh[ww * 16 + s_] - M);
            L += e * Lsh[ww * 16 + s_];
            f32x4 v = *(const f32x4*)(Osh + ww * 2048 + s_ * 128 + d_);
            #pragma unroll
            for (int r = 0; r < 4; ++r) oa[r] += e * v[r];
        }
        const float inv = 1.f / L;
        f16x4 res = {(f16)(oa[0] * inv), (f16)(oa[1] * inv),
                     (f16)(oa[2] * inv), (f16)(oa[3] * inv)};
        *(f16x4*)(Ow + (size_t)(b * 16 + s_) * HID + hh * 128 + d_) = res;
    }
}

extern "C" void kernel_launch(void* const* d_in, const int* in_sizes, int n_in,
                              void* d_out, int out_size, void* d_ws, size_t ws_size,
                              hipStream_t stream) {
    const float* h  = (const float*)d_in[0];
    const float* Wq = (const float*)d_in[1];
    const float* Wk = (const float*)d_in[2];
    const float* Wv = (const float*)d_in[3];
    const float* Wo = (const float*)d_in[4];
    const float* Kc = (const float*)d_in[5];
    const float* Vc = (const float*)d_in[6];
    const int* pos  = (const int*)d_in[7];
    float* out = (float*)d_out;

    f16* hws = (f16*)d_ws;            // 128*4096 f16 = 1 MB
    f16* Qw  = hws + ROWS * HID;
    f16* Kw  = Qw + ROWS * HID;
    f16* Vw  = Kw + ROWS * HID;
    f16* Ow  = Vw + ROWS * HID;

    k_cvt<<<256, 256, 0, stream>>>(h, hws);
    k_proj<<<768, 256, 0, stream>>>(hws, Wq, Wk, Wv, Qw, Kw, Vw);
    k_attn<<<256, 512, 0, stream>>>(Qw, Kw, Vw, Kc, Vc, pos, Ow);
    k_oproj<<<256, 256, 0, stream>>>(Ow, Wo, out);
}